// Round 7
// baseline (2015.974 us; speedup 1.0000x reference)
//
#include <hip/hip_runtime.h>

// Ocean advection + 3x3 binomial smoothing, 48 steps, fp32.
//
// TEMPORAL FUSION x4: each kernel performs FOUR advect+smooth steps with all
// intermediates in registers. 12 dispatches. Unique traffic per step ~1/4.
//
// ROUND-7 NOTES: occupancy is pinned at 2 blocks/CU regardless of grid
// (round-6: doubling grid -> 2 sequential generations, T_iter invariant
// ~1.9us). T_iter is delivered-BW-bound -> the lever is BYTES: K=3 -> K=4.
// SH=16 restored (round-6's SH=8 halo overhead regressed).
//
// fused4_kernel (1-row-per-stage skew, 4 lgkm-only barriers/iter):
//   iteration j (a = h0-7+j), full unroll, ring slot = row & 7 (h0%8==0):
//     loads: T row a+2, ug/vg row a+1, mask row a+1 (1 iter ahead;
//            u/g FIFO depth 8, m depth 9 - reused across stages)
//     A1 = advect(T)   @ a    -> publish; B1
//     S1 = smooth(A1)  @ a-1  -> publish
//     A2 = advect(S1)  @ a-2  -> publish; B2
//     S2 = smooth(A2)  @ a-3  -> publish
//     A3 = advect(S2)  @ a-4  -> publish; B3
//     S3 = smooth(A3)  @ a-5  -> publish
//     A4 = advect(S3)  @ a-6  -> publish; B4
//     out= smooth(A4)  @ a-7  -> global store
//   Cross-wave x-halo via LDS edge rings (8-row ring x wave x {first,last}
//   col); every cross-wave read is >=1 barrier after its publish; ring depth
//   8 => WAR distance >=6 barriers. Raw s_barrier + lgkmcnt(0) only ->
//   global prefetches stay in flight.
//   Spill tripwire: WRITE_SIZE must stay 32768 KB (VGPR est ~165 < 256 cap).

#define DEG2RAD 0.017453292519943295f
#define R_EARTH 6371000.0f
#define DT_S 600.0f

constexpr int NT    = 256;   // threads per block
constexpr int STRIP = 8;     // legacy stream kernel: rows per wave
constexpr int WPW   = 256;   // legacy stream kernel: cols per wave

__global__ __launch_bounds__(256)
void prep_kernel(const float* __restrict__ lat, const float* __restrict__ lon,
                 float* __restrict__ coef, int H) {
    int h = blockIdx.x * blockDim.x + threadIdx.x;
    if (h < H) {
        float dlon = lon[1] - lon[0];
        coef[h] = 1.0f / (R_EARTH * DEG2RAD * dlon * cosf(lat[h] * DEG2RAD));
    }
    if (h == 0) {
        float dlat = lat[1] - lat[0];
        coef[H] = 1.0f / (R_EARTH * DEG2RAD * dlat);
    }
}

// ------------------------- fused 4-step kernel -----------------------------
constexpr int FWAVES = 4;    // waves per block, FWAVES*256 must == W
constexpr int SH4    = 16;   // output rows per block chunk (SH4 % 8 == 0!)
constexpr int NITER4 = SH4 + 14;

__global__ __launch_bounds__(256, 2)
void fused4_kernel(const float* __restrict__ Tin, const float* __restrict__ ug,
                   const float* __restrict__ vg, const float* __restrict__ mask,
                   const float* __restrict__ coef, float* __restrict__ Tout,
                   int H, int W) {
    const int lane = threadIdx.x & 63;
    const int wv   = threadIdx.x >> 6;
    const int h0   = blockIdx.x * SH4;
    const int b    = blockIdx.y;
    const int gw   = (wv << 8) + (lane << 2);
    const size_t plane = (size_t)H * W;
    const float* __restrict__ Tb  = Tin + b * plane;
    const float* __restrict__ ugb = ug  + b * plane;
    const float* __restrict__ vgb = vg  + b * plane;
    float* __restrict__ To = Tout + b * plane;
    const float inv_dy = coef[H];
    const bool isL = (lane == 0), isR = (lane == 63);
    const bool domL = (wv == 0), domR = (wv == FWAVES - 1);

    // edge rings: [row & 7][wave][0 = first col, 1 = last col]
    __shared__ float eT [8][FWAVES][2];
    __shared__ float eA1[8][FWAVES][2];
    __shared__ float eS1[8][FWAVES][2];
    __shared__ float eA2[8][FWAVES][2];
    __shared__ float eS2[8][FWAVES][2];
    __shared__ float eA3[8][FWAVES][2];
    __shared__ float eS3[8][FWAVES][2];
    __shared__ float eA4[8][FWAVES][2];

    auto rowc = [&](int r) { return min(max(r, 0), H - 1); };
    auto ld4 = [&](const float* __restrict__ p, int r) -> float4 {
        return *(const float4*)(p + (size_t)rowc(r) * W + gw);
    };
    const float4 z4 = make_float4(0.f, 0.f, 0.f, 0.f);

    // ---- warm-up: after the j=0 roll, t0..t3 = rows a-1..a+2 (a = h0-7) ----
    float4 t0 = z4;
    float4 t1 = ld4(Tb, h0 - 8);
    float4 t2 = ld4(Tb, h0 - 7);
    float4 t3 = ld4(Tb, h0 - 6);
    // FIFOs: slot k holds row (a+1-k) after the roll
    float4 u0 = ld4(ugb, h0 - 7), u1 = z4, u2 = z4, u3 = z4, u4 = z4, u5 = z4, u6 = z4, u7 = z4;
    float4 g0 = ld4(vgb, h0 - 7), g1 = z4, g2 = z4, g3 = z4, g4 = z4, g5 = z4, g6 = z4, g7 = z4;
    float4 m0 = ld4(mask, h0 - 7), m1 = z4, m2 = z4, m3 = z4, m4 = z4, m5 = z4, m6 = z4, m7 = z4, m8 = z4;
    float4 a1p = z4, a1c = z4, a1n = z4;
    float4 s1p = z4, s1c = z4, s1n = z4;
    float4 a2p = z4, a2c = z4, a2n = z4;
    float4 s2p = z4, s2c = z4, s2n = z4;
    float4 a3p = z4, a3c = z4, a3n = z4;
    float4 s3p = z4, s3c = z4, s3n = z4;
    float4 a4p = z4, a4c = z4, a4n = z4;

    // pre-publish eT rows h0-7 (slot 1) and h0-6 (slot 2)  [h0 % 8 == 0]
    if (isL) { eT[1][wv][0] = t2.x; eT[2][wv][0] = t3.x; }
    if (isR) { eT[1][wv][1] = t2.w; eT[2][wv][1] = t3.w; }
    asm volatile("s_waitcnt lgkmcnt(0)" ::: "memory");
    __builtin_amdgcn_s_barrier();

    #pragma unroll
    for (int j = 0; j < NITER4; ++j) {
        const int a = h0 - 7 + j;               // A1 row; a & 7 == (j+1) & 7
        // ring slots for rows a+1 .. a-8 (row r -> r & 7):
        const int sl_a1p = (j + 2) & 7;         // row a+1
        const int sl_a   = (j + 1) & 7;         // row a
        const int sl_m1  = (j + 0) & 7;         // row a-1
        const int sl_m2  = (j + 7) & 7;         // row a-2
        const int sl_m3  = (j + 6) & 7;         // row a-3
        const int sl_m4  = (j + 5) & 7;         // row a-4
        const int sl_m5  = (j + 4) & 7;         // row a-5
        const int sl_m6  = (j + 3) & 7;         // row a-6
        const int sl_m7  = (j + 2) & 7;         // row a-7 (aliases a+1; diff rings)
        const int sl_m8  = (j + 1) & 7;         // row a-8 (aliases a;   diff rings)

        // ---- roll chains/FIFOs, issue loads (consumed next iter) ----
        t0 = t1; t1 = t2; t2 = t3; t3 = ld4(Tb, a + 2);
        u7 = u6; u6 = u5; u5 = u4; u4 = u3; u3 = u2; u2 = u1; u1 = u0; u0 = ld4(ugb, a + 1);
        g7 = g6; g6 = g5; g5 = g4; g4 = g3; g3 = g2; g2 = g1; g1 = g0; g0 = ld4(vgb, a + 1);
        m8 = m7; m7 = m6; m6 = m5; m5 = m4; m4 = m3; m3 = m2; m2 = m1; m1 = m0; m0 = ld4(mask, a + 1);

        // publish T edges for row a+1 (t2: load completed last iteration)
        if (isL) eT[sl_a1p][wv][0] = t2.x;
        if (isR) eT[sl_a1p][wv][1] = t2.w;

        // ---------------- A1: advect T at row a ----------------
        float4 a1_new = z4;
        if (a >= 0 && a < H) {
            const float ix  = coef[a];
            const float sy  = (a == 0 || a == H - 1) ? inv_dy : 0.5f * inv_dy;
            const float sxh = 0.5f * ix;
            float cL = __shfl_up(t1.w, 1);
            float cR = __shfl_down(t1.x, 1);
            float sxx = sxh, sxw = sxh;
            if (isL) { if (domL) { cL = t1.x; sxx = ix; } else cL = eT[sl_a][wv - 1][1]; }
            if (isR) { if (domR) { cR = t1.w; sxw = ix; } else cR = eT[sl_a][wv + 1][0]; }
            a1_new.x = t1.x + DT_S * (-(u1.x * ((t1.y - cL ) * sxx) + g1.x * ((t2.x - t0.x) * sy)) * m1.x);
            a1_new.y = t1.y + DT_S * (-(u1.y * ((t1.z - t1.x) * sxh) + g1.y * ((t2.y - t0.y) * sy)) * m1.y);
            a1_new.z = t1.z + DT_S * (-(u1.z * ((t1.w - t1.y) * sxh) + g1.z * ((t2.z - t0.z) * sy)) * m1.z);
            a1_new.w = t1.w + DT_S * (-(u1.w * ((cR  - t1.z) * sxw) + g1.w * ((t2.w - t0.w) * sy)) * m1.w);
        }
        if (isL) eA1[sl_a][wv][0] = a1_new.x;
        if (isR) eA1[sl_a][wv][1] = a1_new.w;
        a1n = a1_new;

        // B1 (lgkm-only: global prefetches stay in flight)
        asm volatile("s_waitcnt lgkmcnt(0)" ::: "memory");
        __builtin_amdgcn_s_barrier();

        // ---------------- S1: smooth A1 at row a-1 ----------------
        float4 s1_new = z4;
        if (j >= 2) {
            const int s = a - 1;
            if (s >= 0 && s < H) {
                float4 v;
                v.x = a1p.x + 2.f * a1c.x + a1n.x;
                v.y = a1p.y + 2.f * a1c.y + a1n.y;
                v.z = a1p.z + 2.f * a1c.z + a1n.z;
                v.w = a1p.w + 2.f * a1c.w + a1n.w;
                float vL = __shfl_up(v.w, 1);
                float vR = __shfl_down(v.x, 1);
                if (isL) vL = domL ? 0.f
                    : (eA1[sl_m2][wv - 1][1] + 2.f * eA1[sl_m1][wv - 1][1] + eA1[sl_a][wv - 1][1]);
                if (isR) vR = domR ? 0.f
                    : (eA1[sl_m2][wv + 1][0] + 2.f * eA1[sl_m1][wv + 1][0] + eA1[sl_a][wv + 1][0]);
                s1_new.x = (vL  + 2.f * v.x + v.y) * 0.0625f * m2.x;
                s1_new.y = (v.x + 2.f * v.y + v.z) * 0.0625f * m2.y;
                s1_new.z = (v.y + 2.f * v.z + v.w) * 0.0625f * m2.z;
                s1_new.w = (v.z + 2.f * v.w + vR ) * 0.0625f * m2.w;
            }
            if (isL) eS1[sl_m1][wv][0] = s1_new.x;
            if (isR) eS1[sl_m1][wv][1] = s1_new.w;
        }
        a1p = a1c; a1c = a1n;
        s1n = s1_new;

        // ---------------- A2: advect S1 at row a-2 ----------------
        float4 a2_new = z4;
        if (j >= 4) {
            const int q = a - 2;
            if (q >= 0 && q < H) {
                const float ix  = coef[q];
                const float sxh = 0.5f * ix;
                float cL = __shfl_up(s1c.w, 1);
                float cR = __shfl_down(s1c.x, 1);
                float sxx = sxh, sxw = sxh;
                if (isL) { if (domL) { cL = s1c.x; sxx = ix; } else cL = eS1[sl_m2][wv - 1][1]; }
                if (isR) { if (domR) { cR = s1c.w; sxw = ix; } else cR = eS1[sl_m2][wv + 1][0]; }
                const float4 yl = (q == 0)     ? s1c : s1p;
                const float4 yh = (q == H - 1) ? s1c : s1n;
                const float sy  = (q == 0 || q == H - 1) ? inv_dy : 0.5f * inv_dy;
                a2_new.x = s1c.x + DT_S * (-(u3.x * ((s1c.y - cL  ) * sxx) + g3.x * ((yh.x - yl.x) * sy)) * m3.x);
                a2_new.y = s1c.y + DT_S * (-(u3.y * ((s1c.z - s1c.x) * sxh) + g3.y * ((yh.y - yl.y) * sy)) * m3.y);
                a2_new.z = s1c.z + DT_S * (-(u3.z * ((s1c.w - s1c.y) * sxh) + g3.z * ((yh.z - yl.z) * sy)) * m3.z);
                a2_new.w = s1c.w + DT_S * (-(u3.w * ((cR   - s1c.z) * sxw) + g3.w * ((yh.w - yl.w) * sy)) * m3.w);
            }
            if (isL) eA2[sl_m2][wv][0] = a2_new.x;
            if (isR) eA2[sl_m2][wv][1] = a2_new.w;
        }
        s1p = s1c; s1c = s1n;
        a2n = a2_new;

        // B2
        asm volatile("s_waitcnt lgkmcnt(0)" ::: "memory");
        __builtin_amdgcn_s_barrier();

        // ---------------- S2: smooth A2 at row a-3 ----------------
        float4 s2_new = z4;
        if (j >= 6) {
            const int s = a - 3;
            if (s >= 0 && s < H) {
                float4 v;
                v.x = a2p.x + 2.f * a2c.x + a2n.x;
                v.y = a2p.y + 2.f * a2c.y + a2n.y;
                v.z = a2p.z + 2.f * a2c.z + a2n.z;
                v.w = a2p.w + 2.f * a2c.w + a2n.w;
                float vL = __shfl_up(v.w, 1);
                float vR = __shfl_down(v.x, 1);
                if (isL) vL = domL ? 0.f
                    : (eA2[sl_m4][wv - 1][1] + 2.f * eA2[sl_m3][wv - 1][1] + eA2[sl_m2][wv - 1][1]);
                if (isR) vR = domR ? 0.f
                    : (eA2[sl_m4][wv + 1][0] + 2.f * eA2[sl_m3][wv + 1][0] + eA2[sl_m2][wv + 1][0]);
                s2_new.x = (vL  + 2.f * v.x + v.y) * 0.0625f * m4.x;
                s2_new.y = (v.x + 2.f * v.y + v.z) * 0.0625f * m4.y;
                s2_new.z = (v.y + 2.f * v.z + v.w) * 0.0625f * m4.z;
                s2_new.w = (v.z + 2.f * v.w + vR ) * 0.0625f * m4.w;
            }
            if (isL) eS2[sl_m3][wv][0] = s2_new.x;
            if (isR) eS2[sl_m3][wv][1] = s2_new.w;
        }
        a2p = a2c; a2c = a2n;
        s2n = s2_new;

        // ---------------- A3: advect S2 at row a-4 ----------------
        float4 a3_new = z4;
        if (j >= 8) {
            const int p = a - 4;
            if (p >= 0 && p < H) {
                const float ix  = coef[p];
                const float sxh = 0.5f * ix;
                float cL = __shfl_up(s2c.w, 1);
                float cR = __shfl_down(s2c.x, 1);
                float sxx = sxh, sxw = sxh;
                if (isL) { if (domL) { cL = s2c.x; sxx = ix; } else cL = eS2[sl_m4][wv - 1][1]; }
                if (isR) { if (domR) { cR = s2c.w; sxw = ix; } else cR = eS2[sl_m4][wv + 1][0]; }
                const float4 yl = (p == 0)     ? s2c : s2p;
                const float4 yh = (p == H - 1) ? s2c : s2n;
                const float sy  = (p == 0 || p == H - 1) ? inv_dy : 0.5f * inv_dy;
                a3_new.x = s2c.x + DT_S * (-(u5.x * ((s2c.y - cL  ) * sxx) + g5.x * ((yh.x - yl.x) * sy)) * m5.x);
                a3_new.y = s2c.y + DT_S * (-(u5.y * ((s2c.z - s2c.x) * sxh) + g5.y * ((yh.y - yl.y) * sy)) * m5.y);
                a3_new.z = s2c.z + DT_S * (-(u5.z * ((s2c.w - s2c.y) * sxh) + g5.z * ((yh.z - yl.z) * sy)) * m5.z);
                a3_new.w = s2c.w + DT_S * (-(u5.w * ((cR   - s2c.z) * sxw) + g5.w * ((yh.w - yl.w) * sy)) * m5.w);
            }
            if (isL) eA3[sl_m4][wv][0] = a3_new.x;
            if (isR) eA3[sl_m4][wv][1] = a3_new.w;
        }
        s2p = s2c; s2c = s2n;
        a3n = a3_new;

        // B3
        asm volatile("s_waitcnt lgkmcnt(0)" ::: "memory");
        __builtin_amdgcn_s_barrier();

        // ---------------- S3: smooth A3 at row a-5 ----------------
        float4 s3_new = z4;
        if (j >= 10) {
            const int s = a - 5;
            if (s >= 0 && s < H) {
                float4 v;
                v.x = a3p.x + 2.f * a3c.x + a3n.x;
                v.y = a3p.y + 2.f * a3c.y + a3n.y;
                v.z = a3p.z + 2.f * a3c.z + a3n.z;
                v.w = a3p.w + 2.f * a3c.w + a3n.w;
                float vL = __shfl_up(v.w, 1);
                float vR = __shfl_down(v.x, 1);
                if (isL) vL = domL ? 0.f
                    : (eA3[sl_m6][wv - 1][1] + 2.f * eA3[sl_m5][wv - 1][1] + eA3[sl_m4][wv - 1][1]);
                if (isR) vR = domR ? 0.f
                    : (eA3[sl_m6][wv + 1][0] + 2.f * eA3[sl_m5][wv + 1][0] + eA3[sl_m4][wv + 1][0]);
                s3_new.x = (vL  + 2.f * v.x + v.y) * 0.0625f * m6.x;
                s3_new.y = (v.x + 2.f * v.y + v.z) * 0.0625f * m6.y;
                s3_new.z = (v.y + 2.f * v.z + v.w) * 0.0625f * m6.z;
                s3_new.w = (v.z + 2.f * v.w + vR ) * 0.0625f * m6.w;
            }
            if (isL) eS3[sl_m5][wv][0] = s3_new.x;
            if (isR) eS3[sl_m5][wv][1] = s3_new.w;
        }
        a3p = a3c; a3c = a3n;
        s3n = s3_new;

        // ---------------- A4: advect S3 at row a-6 ----------------
        float4 a4_new = z4;
        if (j >= 12) {
            const int p = a - 6;
            if (p >= 0 && p < H) {
                const float ix  = coef[p];
                const float sxh = 0.5f * ix;
                float cL = __shfl_up(s3c.w, 1);
                float cR = __shfl_down(s3c.x, 1);
                float sxx = sxh, sxw = sxh;
                if (isL) { if (domL) { cL = s3c.x; sxx = ix; } else cL = eS3[sl_m6][wv - 1][1]; }
                if (isR) { if (domR) { cR = s3c.w; sxw = ix; } else cR = eS3[sl_m6][wv + 1][0]; }
                const float4 yl = (p == 0)     ? s3c : s3p;
                const float4 yh = (p == H - 1) ? s3c : s3n;
                const float sy  = (p == 0 || p == H - 1) ? inv_dy : 0.5f * inv_dy;
                a4_new.x = s3c.x + DT_S * (-(u7.x * ((s3c.y - cL  ) * sxx) + g7.x * ((yh.x - yl.x) * sy)) * m7.x);
                a4_new.y = s3c.y + DT_S * (-(u7.y * ((s3c.z - s3c.x) * sxh) + g7.y * ((yh.y - yl.y) * sy)) * m7.y);
                a4_new.z = s3c.z + DT_S * (-(u7.z * ((s3c.w - s3c.y) * sxh) + g7.z * ((yh.z - yl.z) * sy)) * m7.z);
                a4_new.w = s3c.w + DT_S * (-(u7.w * ((cR   - s3c.z) * sxw) + g7.w * ((yh.w - yl.w) * sy)) * m7.w);
            }
            if (isL) eA4[sl_m6][wv][0] = a4_new.x;
            if (isR) eA4[sl_m6][wv][1] = a4_new.w;
        }
        s3p = s3c; s3c = s3n;
        a4n = a4_new;

        // B4
        asm volatile("s_waitcnt lgkmcnt(0)" ::: "memory");
        __builtin_amdgcn_s_barrier();

        // ---------------- out: smooth A4 at row a-7 ----------------
        if (j >= 14) {
            const int r = a - 7;                 // in [h0, h0+SH4)
            if (r < H) {
                float4 v;
                v.x = a4p.x + 2.f * a4c.x + a4n.x;
                v.y = a4p.y + 2.f * a4c.y + a4n.y;
                v.z = a4p.z + 2.f * a4c.z + a4n.z;
                v.w = a4p.w + 2.f * a4c.w + a4n.w;
                float vL = __shfl_up(v.w, 1);
                float vR = __shfl_down(v.x, 1);
                if (isL) vL = domL ? 0.f
                    : (eA4[sl_m8][wv - 1][1] + 2.f * eA4[sl_m7][wv - 1][1] + eA4[sl_m6][wv - 1][1]);
                if (isR) vR = domR ? 0.f
                    : (eA4[sl_m8][wv + 1][0] + 2.f * eA4[sl_m7][wv + 1][0] + eA4[sl_m6][wv + 1][0]);
                float4 o;
                o.x = (vL  + 2.f * v.x + v.y) * 0.0625f * m8.x;
                o.y = (v.x + 2.f * v.y + v.z) * 0.0625f * m8.y;
                o.z = (v.y + 2.f * v.z + v.w) * 0.0625f * m8.z;
                o.w = (v.z + 2.f * v.w + vR ) * 0.0625f * m8.w;
                *(float4*)(To + (size_t)r * W + gw) = o;
            }
        }
        a4p = a4c; a4c = a4n;
    }
}

// --------- legacy single-step stream kernel (fallback, W % 256 == 0) -------
__global__ __launch_bounds__(256, 4)
void stream_kernel(const float* __restrict__ Tin, const float* __restrict__ ug,
                   const float* __restrict__ vg, const float* __restrict__ mask,
                   const float* __restrict__ coef, float* __restrict__ Tout,
                   int H, int W) {
    const int lane = threadIdx.x & 63;
    const int wv   = threadIdx.x >> 6;
    const int ws   = blockIdx.x * WPW;
    const int hs   = (blockIdx.y * 4 + wv) * STRIP;
    const int b    = blockIdx.z;
    if (hs >= H) return;
    const size_t plane = (size_t)H * W;
    const float* __restrict__ Tb  = Tin + b * plane;
    const float* __restrict__ ugb = ug  + b * plane;
    const float* __restrict__ vgb = vg  + b * plane;
    float* __restrict__ To = Tout + b * plane;
    const float inv_dy = coef[H];
    const bool atL = (ws == 0);
    const bool atR = (ws + WPW >= W);
    const bool isL = (lane == 0);
    const bool isR = (lane == 63);
    const int gw = ws + 4 * lane;

    auto clampr = [&](int r) { return min(max(r, 0), H - 1); };
    auto ldT = [&](int r) -> float4 {
        return *(const float4*)(Tb + (size_t)clampr(r) * W + gw);
    };
    auto ldL = [&](int r) -> float2 {
        float4 q = *(const float4*)(Tb + (size_t)clampr(r) * W + (ws - 4));
        return make_float2(q.z, q.w);
    };
    auto ldR = [&](int r) -> float2 {
        float4 q = *(const float4*)(Tb + (size_t)clampr(r) * W + (ws + WPW));
        return make_float2(q.x, q.y);
    };

    float4 tp, tc, tn;
    float  tLp_w = 0.f; float2 tLc = make_float2(0.f, 0.f), tLn = make_float2(0.f, 0.f);
    float  tRp_x = 0.f; float2 tRc = make_float2(0.f, 0.f), tRn = make_float2(0.f, 0.f);

    auto roll = [&](int rnext) {
        tp = tc; tc = tn; tn = ldT(rnext);
        if (!atL) { tLp_w = tLc.y; tLc = tLn; tLn = ldL(rnext); }
        if (!atR) { tRp_x = tRc.x; tRc = tRn; tRn = ldR(rnext); }
    };

    auto advrow = [&](int r, float4& a, float& aL, float& aR, float4& mOut) {
        if (r < 0 || r >= H) {
            a = make_float4(0.f, 0.f, 0.f, 0.f); aL = 0.f; aR = 0.f;
            mOut = make_float4(0.f, 0.f, 0.f, 0.f); return;
        }
        const size_t ro = (size_t)r * W;
        const float ix  = coef[r];
        const float sy  = (r == 0 || r == H - 1) ? inv_dy : 0.5f * inv_dy;
        const float sxh = 0.5f * ix;
        float4 u4 = *(const float4*)(ugb + ro + gw);
        float4 g4 = *(const float4*)(vgb + ro + gw);
        float4 m4 = *(const float4*)(mask + ro + gw);
        float cLw = __shfl_up(tc.w, 1);
        float cRx = __shfl_down(tc.x, 1);
        float sxx = sxh, sxw = sxh;
        if (isL) { if (atL) { cLw = tc.x; sxx = ix; } else { cLw = tLc.y; } }
        if (isR) { if (atR) { cRx = tc.w; sxw = ix; } else { cRx = tRc.x; } }
        a.x = tc.x + DT_S * (-(u4.x * ((tc.y - cLw) * sxx) + g4.x * ((tn.x - tp.x) * sy)) * m4.x);
        a.y = tc.y + DT_S * (-(u4.y * ((tc.z - tc.x) * sxh) + g4.y * ((tn.y - tp.y) * sy)) * m4.y);
        a.z = tc.z + DT_S * (-(u4.z * ((tc.w - tc.y) * sxh) + g4.z * ((tn.z - tp.z) * sy)) * m4.z);
        a.w = tc.w + DT_S * (-(u4.w * ((cRx - tc.z) * sxw) + g4.w * ((tn.w - tp.w) * sy)) * m4.w);
        if (!atL) {
            float uL = ((const float4*)(ugb + ro + (ws - 4)))->w;
            float gL = ((const float4*)(vgb + ro + (ws - 4)))->w;
            float mL = ((const float4*)(mask + ro + (ws - 4)))->w;
            aL = tLc.y + DT_S * (-(uL * ((tc.x - tLc.x) * sxh) + gL * ((tLn.y - tLp_w) * sy)) * mL);
        } else aL = 0.f;
        if (!atR) {
            float uR = ((const float4*)(ugb + ro + (ws + WPW)))->x;
            float gR = ((const float4*)(vgb + ro + (ws + WPW)))->x;
            float mR = ((const float4*)(mask + ro + (ws + WPW)))->x;
            aR = tRc.x + DT_S * (-(uR * ((tRc.y - tc.w) * sxh) + gR * ((tRn.x - tRp_x) * sy)) * mR);
        } else aR = 0.f;
        mOut = m4;
    };

    tp = ldT(hs - 2); tc = ldT(hs - 1); tn = ldT(hs);
    if (!atL) { float2 q = ldL(hs - 2); tLp_w = q.y; tLc = ldL(hs - 1); tLn = ldL(hs); }
    if (!atR) { float2 q = ldR(hs - 2); tRp_x = q.x; tRc = ldR(hs - 1); tRn = ldR(hs); }

    float4 ap, ac, an, mC, mN, mdum;
    float aLp, aLc, aLn, aRp, aRc, aRn;
    advrow(hs - 1, ap, aLp, aRp, mdum);
    roll(hs + 1);
    advrow(hs, ac, aLc, aRc, mC);

    #pragma unroll
    for (int i = 0; i < STRIP; ++i) {
        const int go = hs + i;
        roll(go + 2);
        advrow(go + 1, an, aLn, aRn, mN);
        if (go < H) {
            float4 v;
            v.x = ap.x + 2.f * ac.x + an.x;
            v.y = ap.y + 2.f * ac.y + an.y;
            v.z = ap.z + 2.f * ac.z + an.z;
            v.w = ap.w + 2.f * ac.w + an.w;
            float vL  = aLp + 2.f * aLc + aLn;
            float vR  = aRp + 2.f * aRc + aRn;
            float vLw = __shfl_up(v.w, 1);
            float vRx = __shfl_down(v.x, 1);
            if (isL) vLw = atL ? 0.f : vL;
            if (isR) vRx = atR ? 0.f : vR;
            float4 o;
            o.x = (vLw + 2.f * v.x + v.y) * 0.0625f * mC.x;
            o.y = (v.x + 2.f * v.y + v.z) * 0.0625f * mC.y;
            o.z = (v.y + 2.f * v.z + v.w) * 0.0625f * mC.z;
            o.w = (v.z + 2.f * v.w + vRx) * 0.0625f * mC.w;
            *(float4*)(To + (size_t)go * W + gw) = o;
        }
        ap = ac; ac = an;
        aLp = aLc; aLc = aLn; aRp = aRc; aRc = aRn;
        mC = mN;
    }
}

// ---------- generic fallback (round-1 LDS tile kernel, validated) ----------
constexpr int FTW = 64, FTH = 32;
constexpr int FSTW = FTW + 4, FSTH = FTH + 4;
constexpr int FMTW = FTW + 2, FMTH = FTH + 2;

__global__ __launch_bounds__(256)
void step_tile(const float* __restrict__ Tin, const float* __restrict__ ug,
               const float* __restrict__ vg, const float* __restrict__ mask,
               const float* __restrict__ coef, float* __restrict__ Tout,
               int H, int W) {
    __shared__ float sT[FSTH][FSTW];
    __shared__ float sM[FMTH][FMTW];
    const int tid = threadIdx.x;
    const int w0 = blockIdx.x * FTW;
    const int h0 = blockIdx.y * FTH;
    const int b  = blockIdx.z;
    const long plane = (long)H * W;
    const float* Tb  = Tin + b * plane;
    const float* ugb = ug  + b * plane;
    const float* vgb = vg  + b * plane;
    const float inv_dy = coef[H];

    for (int i = tid; i < FSTH * FSTW; i += NT) {
        int r = i / FSTW, c = i - r * FSTW;
        int gh = min(max(h0 - 2 + r, 0), H - 1);
        int gw = min(max(w0 - 2 + c, 0), W - 1);
        sT[r][c] = Tb[gh * W + gw];
    }
    __syncthreads();
    for (int i = tid; i < FMTH * FMTW; i += NT) {
        int r = i / FMTW, c = i - r * FMTW;
        int gh = h0 - 1 + r, gw = w0 - 1 + c;
        float v = 0.0f;
        if (gh >= 0 && gh < H && gw >= 0 && gw < W) {
            int sr = r + 1, sc = c + 1;
            float ndy = sT[sr + 1][sc] - sT[sr - 1][sc];
            float ndx = sT[sr][sc + 1] - sT[sr][sc - 1];
            float sy  = (gh == 0 || gh == H - 1) ? inv_dy : 0.5f * inv_dy;
            float ix  = coef[gh];
            float sx  = (gw == 0 || gw == W - 1) ? ix : 0.5f * ix;
            int   gi  = gh * W + gw;
            float F   = -(ugb[gi] * (ndx * sx) + vgb[gi] * (ndy * sy)) * mask[gi];
            v = sT[sr][sc] + DT_S * F;
        }
        sM[r][c] = v;
    }
    __syncthreads();
    float* To = Tout + b * plane;
    for (int i = tid; i < FTH * FTW; i += NT) {
        int r = i >> 6, c = i & (FTW - 1);
        int gh = h0 + r, gw = w0 + c;
        if (gh < H && gw < W) {
            int sr = r + 1, sc = c + 1;
            float s = (sM[sr-1][sc-1] + sM[sr-1][sc+1] + sM[sr+1][sc-1] + sM[sr+1][sc+1])
                    + 2.0f * (sM[sr-1][sc] + sM[sr+1][sc] + sM[sr][sc-1] + sM[sr][sc+1])
                    + 4.0f * sM[sr][sc];
            To[gh * W + gw] = s * 0.0625f * mask[gh * W + gw];
        }
    }
}

extern "C" void kernel_launch(void* const* d_in, const int* in_sizes, int n_in,
                              void* d_out, int out_size, void* d_ws, size_t ws_size,
                              hipStream_t stream) {
    const float* T0   = (const float*)d_in[0];
    const float* ug   = (const float*)d_in[1];
    const float* vg   = (const float*)d_in[2];
    const float* lat  = (const float*)d_in[3];
    const float* lon  = (const float*)d_in[4];
    const float* mask = (const float*)d_in[5];

    const int H = in_sizes[3];
    const int W = in_sizes[4];
    const int B = in_sizes[0] / (H * W);

    float* out  = (float*)d_out;
    float* ping = (float*)d_ws;                 // B*H*W floats
    float* coef = ping + (size_t)B * H * W;     // H+1 floats: 1/dx[h], then 1/dy

    prep_kernel<<<dim3((H + NT - 1) / NT), dim3(NT), 0, stream>>>(lat, lon, coef, H);

    const int STEPS = 48;

    if (W == FWAVES * 256) {
        // fused 4-step path: 12 launches, each = 4 simulated steps
        dim3 gridF4((H + SH4 - 1) / SH4, B);
        const int NLAUNCH = STEPS / 4;          // 12, even -> last dst == out
        for (int i = 0; i < NLAUNCH; ++i) {
            const float* src = (i == 0) ? T0 : ((i & 1) ? ping : out);
            float*       dst = (i & 1) ? out : ping;
            fused4_kernel<<<gridF4, dim3(NT), 0, stream>>>(src, ug, vg, mask, coef, dst, H, W);
        }
    } else {
        const bool fast = (W % WPW) == 0;
        dim3 gridS(W / (fast ? WPW : 1), (H + 4 * STRIP - 1) / (4 * STRIP), B);
        dim3 gridF((W + FTW - 1) / FTW, (H + FTH - 1) / FTH, B);
        for (int i = 0; i < STEPS; ++i) {
            const float* src = (i == 0) ? T0 : ((i & 1) ? ping : out);
            float*       dst = (i & 1) ? out : ping;
            if (fast)
                stream_kernel<<<gridS, dim3(NT), 0, stream>>>(src, ug, vg, mask, coef, dst, H, W);
            else
                step_tile<<<gridF, dim3(NT), 0, stream>>>(src, ug, vg, mask, coef, dst, H, W);
        }
    }
}

// Round 8
// 1616.368 us; speedup vs baseline: 1.2472x; 1.2472x over previous
//
#include <hip/hip_runtime.h>

// Ocean advection + 3x3 binomial smoothing, 48 steps, fp32.
//
// TEMPORAL FUSION x4: each kernel performs FOUR advect+smooth steps with all
// intermediates in registers. 12 dispatches. Unique traffic per step ~1/4.
//
// ROUND-8 CHANGE: __launch_bounds__(256,2) -> (256,1). Empirical law from
// rounds 3/7: (256,N) caps VGPR at 256/N. K=4's ~165-reg live set spilled
// at the 128 cap (WRITE_SIZE 32MB->85MB, VGPR pinned 128, 2016us). (256,1)
// -> cap 256; at VGPR<=256 occupancy stays 2 waves/SIMD = 2 blocks/CU (the
// same as every healthy variant), with no spills.
// Spill tripwire: WRITE_SIZE must be 32768 KB exactly.
//
// fused4_kernel (1-row-per-stage skew, 4 lgkm-only barriers/iter):
//   iteration j (a = h0-7+j), full unroll, ring slot = row & 7 (h0%8==0):
//     loads: T row a+2, ug/vg row a+1, mask row a+1 (1 iter ahead;
//            u/g FIFO depth 8, m depth 9 - reused across stages)
//     A1 = advect(T)   @ a    -> publish; B1
//     S1 = smooth(A1)  @ a-1  -> publish
//     A2 = advect(S1)  @ a-2  -> publish; B2
//     S2 = smooth(A2)  @ a-3  -> publish
//     A3 = advect(S2)  @ a-4  -> publish; B3
//     S3 = smooth(A3)  @ a-5  -> publish
//     A4 = advect(S3)  @ a-6  -> publish; B4
//     out= smooth(A4)  @ a-7  -> global store
//   Cross-wave x-halo via LDS edge rings (8-row ring x wave x {first,last}
//   col); every cross-wave read is >=1 barrier after its publish; ring depth
//   8 => WAR distance >=6 barriers. Raw s_barrier + lgkmcnt(0) only ->
//   global prefetches stay in flight.

#define DEG2RAD 0.017453292519943295f
#define R_EARTH 6371000.0f
#define DT_S 600.0f

constexpr int NT    = 256;   // threads per block
constexpr int STRIP = 8;     // legacy stream kernel: rows per wave
constexpr int WPW   = 256;   // legacy stream kernel: cols per wave

__global__ __launch_bounds__(256)
void prep_kernel(const float* __restrict__ lat, const float* __restrict__ lon,
                 float* __restrict__ coef, int H) {
    int h = blockIdx.x * blockDim.x + threadIdx.x;
    if (h < H) {
        float dlon = lon[1] - lon[0];
        coef[h] = 1.0f / (R_EARTH * DEG2RAD * dlon * cosf(lat[h] * DEG2RAD));
    }
    if (h == 0) {
        float dlat = lat[1] - lat[0];
        coef[H] = 1.0f / (R_EARTH * DEG2RAD * dlat);
    }
}

// ------------------------- fused 4-step kernel -----------------------------
constexpr int FWAVES = 4;    // waves per block, FWAVES*256 must == W
constexpr int SH4    = 16;   // output rows per block chunk (SH4 % 8 == 0!)
constexpr int NITER4 = SH4 + 14;

__global__ __launch_bounds__(256, 1)
void fused4_kernel(const float* __restrict__ Tin, const float* __restrict__ ug,
                   const float* __restrict__ vg, const float* __restrict__ mask,
                   const float* __restrict__ coef, float* __restrict__ Tout,
                   int H, int W) {
    const int lane = threadIdx.x & 63;
    const int wv   = threadIdx.x >> 6;
    const int h0   = blockIdx.x * SH4;
    const int b    = blockIdx.y;
    const int gw   = (wv << 8) + (lane << 2);
    const size_t plane = (size_t)H * W;
    const float* __restrict__ Tb  = Tin + b * plane;
    const float* __restrict__ ugb = ug  + b * plane;
    const float* __restrict__ vgb = vg  + b * plane;
    float* __restrict__ To = Tout + b * plane;
    const float inv_dy = coef[H];
    const bool isL = (lane == 0), isR = (lane == 63);
    const bool domL = (wv == 0), domR = (wv == FWAVES - 1);

    // edge rings: [row & 7][wave][0 = first col, 1 = last col]
    __shared__ float eT [8][FWAVES][2];
    __shared__ float eA1[8][FWAVES][2];
    __shared__ float eS1[8][FWAVES][2];
    __shared__ float eA2[8][FWAVES][2];
    __shared__ float eS2[8][FWAVES][2];
    __shared__ float eA3[8][FWAVES][2];
    __shared__ float eS3[8][FWAVES][2];
    __shared__ float eA4[8][FWAVES][2];

    auto rowc = [&](int r) { return min(max(r, 0), H - 1); };
    auto ld4 = [&](const float* __restrict__ p, int r) -> float4 {
        return *(const float4*)(p + (size_t)rowc(r) * W + gw);
    };
    const float4 z4 = make_float4(0.f, 0.f, 0.f, 0.f);

    // ---- warm-up: after the j=0 roll, t0..t3 = rows a-1..a+2 (a = h0-7) ----
    float4 t0 = z4;
    float4 t1 = ld4(Tb, h0 - 8);
    float4 t2 = ld4(Tb, h0 - 7);
    float4 t3 = ld4(Tb, h0 - 6);
    // FIFOs: slot k holds row (a+1-k) after the roll
    float4 u0 = ld4(ugb, h0 - 7), u1 = z4, u2 = z4, u3 = z4, u4 = z4, u5 = z4, u6 = z4, u7 = z4;
    float4 g0 = ld4(vgb, h0 - 7), g1 = z4, g2 = z4, g3 = z4, g4 = z4, g5 = z4, g6 = z4, g7 = z4;
    float4 m0 = ld4(mask, h0 - 7), m1 = z4, m2 = z4, m3 = z4, m4 = z4, m5 = z4, m6 = z4, m7 = z4, m8 = z4;
    float4 a1p = z4, a1c = z4, a1n = z4;
    float4 s1p = z4, s1c = z4, s1n = z4;
    float4 a2p = z4, a2c = z4, a2n = z4;
    float4 s2p = z4, s2c = z4, s2n = z4;
    float4 a3p = z4, a3c = z4, a3n = z4;
    float4 s3p = z4, s3c = z4, s3n = z4;
    float4 a4p = z4, a4c = z4, a4n = z4;

    // pre-publish eT rows h0-7 (slot 1) and h0-6 (slot 2)  [h0 % 8 == 0]
    if (isL) { eT[1][wv][0] = t2.x; eT[2][wv][0] = t3.x; }
    if (isR) { eT[1][wv][1] = t2.w; eT[2][wv][1] = t3.w; }
    asm volatile("s_waitcnt lgkmcnt(0)" ::: "memory");
    __builtin_amdgcn_s_barrier();

    #pragma unroll
    for (int j = 0; j < NITER4; ++j) {
        const int a = h0 - 7 + j;               // A1 row; a & 7 == (j+1) & 7
        // ring slots for rows a+1 .. a-8 (row r -> r & 7):
        const int sl_a1p = (j + 2) & 7;         // row a+1
        const int sl_a   = (j + 1) & 7;         // row a
        const int sl_m1  = (j + 0) & 7;         // row a-1
        const int sl_m2  = (j + 7) & 7;         // row a-2
        const int sl_m3  = (j + 6) & 7;         // row a-3
        const int sl_m4  = (j + 5) & 7;         // row a-4
        const int sl_m5  = (j + 4) & 7;         // row a-5
        const int sl_m6  = (j + 3) & 7;         // row a-6
        const int sl_m7  = (j + 2) & 7;         // row a-7 (aliases a+1; diff rings)
        const int sl_m8  = (j + 1) & 7;         // row a-8 (aliases a;   diff rings)

        // ---- roll chains/FIFOs, issue loads (consumed next iter) ----
        t0 = t1; t1 = t2; t2 = t3; t3 = ld4(Tb, a + 2);
        u7 = u6; u6 = u5; u5 = u4; u4 = u3; u3 = u2; u2 = u1; u1 = u0; u0 = ld4(ugb, a + 1);
        g7 = g6; g6 = g5; g5 = g4; g4 = g3; g3 = g2; g2 = g1; g1 = g0; g0 = ld4(vgb, a + 1);
        m8 = m7; m7 = m6; m6 = m5; m5 = m4; m4 = m3; m3 = m2; m2 = m1; m1 = m0; m0 = ld4(mask, a + 1);

        // publish T edges for row a+1 (t2: load completed last iteration)
        if (isL) eT[sl_a1p][wv][0] = t2.x;
        if (isR) eT[sl_a1p][wv][1] = t2.w;

        // ---------------- A1: advect T at row a ----------------
        float4 a1_new = z4;
        if (a >= 0 && a < H) {
            const float ix  = coef[a];
            const float sy  = (a == 0 || a == H - 1) ? inv_dy : 0.5f * inv_dy;
            const float sxh = 0.5f * ix;
            float cL = __shfl_up(t1.w, 1);
            float cR = __shfl_down(t1.x, 1);
            float sxx = sxh, sxw = sxh;
            if (isL) { if (domL) { cL = t1.x; sxx = ix; } else cL = eT[sl_a][wv - 1][1]; }
            if (isR) { if (domR) { cR = t1.w; sxw = ix; } else cR = eT[sl_a][wv + 1][0]; }
            a1_new.x = t1.x + DT_S * (-(u1.x * ((t1.y - cL ) * sxx) + g1.x * ((t2.x - t0.x) * sy)) * m1.x);
            a1_new.y = t1.y + DT_S * (-(u1.y * ((t1.z - t1.x) * sxh) + g1.y * ((t2.y - t0.y) * sy)) * m1.y);
            a1_new.z = t1.z + DT_S * (-(u1.z * ((t1.w - t1.y) * sxh) + g1.z * ((t2.z - t0.z) * sy)) * m1.z);
            a1_new.w = t1.w + DT_S * (-(u1.w * ((cR  - t1.z) * sxw) + g1.w * ((t2.w - t0.w) * sy)) * m1.w);
        }
        if (isL) eA1[sl_a][wv][0] = a1_new.x;
        if (isR) eA1[sl_a][wv][1] = a1_new.w;
        a1n = a1_new;

        // B1 (lgkm-only: global prefetches stay in flight)
        asm volatile("s_waitcnt lgkmcnt(0)" ::: "memory");
        __builtin_amdgcn_s_barrier();

        // ---------------- S1: smooth A1 at row a-1 ----------------
        float4 s1_new = z4;
        if (j >= 2) {
            const int s = a - 1;
            if (s >= 0 && s < H) {
                float4 v;
                v.x = a1p.x + 2.f * a1c.x + a1n.x;
                v.y = a1p.y + 2.f * a1c.y + a1n.y;
                v.z = a1p.z + 2.f * a1c.z + a1n.z;
                v.w = a1p.w + 2.f * a1c.w + a1n.w;
                float vL = __shfl_up(v.w, 1);
                float vR = __shfl_down(v.x, 1);
                if (isL) vL = domL ? 0.f
                    : (eA1[sl_m2][wv - 1][1] + 2.f * eA1[sl_m1][wv - 1][1] + eA1[sl_a][wv - 1][1]);
                if (isR) vR = domR ? 0.f
                    : (eA1[sl_m2][wv + 1][0] + 2.f * eA1[sl_m1][wv + 1][0] + eA1[sl_a][wv + 1][0]);
                s1_new.x = (vL  + 2.f * v.x + v.y) * 0.0625f * m2.x;
                s1_new.y = (v.x + 2.f * v.y + v.z) * 0.0625f * m2.y;
                s1_new.z = (v.y + 2.f * v.z + v.w) * 0.0625f * m2.z;
                s1_new.w = (v.z + 2.f * v.w + vR ) * 0.0625f * m2.w;
            }
            if (isL) eS1[sl_m1][wv][0] = s1_new.x;
            if (isR) eS1[sl_m1][wv][1] = s1_new.w;
        }
        a1p = a1c; a1c = a1n;
        s1n = s1_new;

        // ---------------- A2: advect S1 at row a-2 ----------------
        float4 a2_new = z4;
        if (j >= 4) {
            const int q = a - 2;
            if (q >= 0 && q < H) {
                const float ix  = coef[q];
                const float sxh = 0.5f * ix;
                float cL = __shfl_up(s1c.w, 1);
                float cR = __shfl_down(s1c.x, 1);
                float sxx = sxh, sxw = sxh;
                if (isL) { if (domL) { cL = s1c.x; sxx = ix; } else cL = eS1[sl_m2][wv - 1][1]; }
                if (isR) { if (domR) { cR = s1c.w; sxw = ix; } else cR = eS1[sl_m2][wv + 1][0]; }
                const float4 yl = (q == 0)     ? s1c : s1p;
                const float4 yh = (q == H - 1) ? s1c : s1n;
                const float sy  = (q == 0 || q == H - 1) ? inv_dy : 0.5f * inv_dy;
                a2_new.x = s1c.x + DT_S * (-(u3.x * ((s1c.y - cL  ) * sxx) + g3.x * ((yh.x - yl.x) * sy)) * m3.x);
                a2_new.y = s1c.y + DT_S * (-(u3.y * ((s1c.z - s1c.x) * sxh) + g3.y * ((yh.y - yl.y) * sy)) * m3.y);
                a2_new.z = s1c.z + DT_S * (-(u3.z * ((s1c.w - s1c.y) * sxh) + g3.z * ((yh.z - yl.z) * sy)) * m3.z);
                a2_new.w = s1c.w + DT_S * (-(u3.w * ((cR   - s1c.z) * sxw) + g3.w * ((yh.w - yl.w) * sy)) * m3.w);
            }
            if (isL) eA2[sl_m2][wv][0] = a2_new.x;
            if (isR) eA2[sl_m2][wv][1] = a2_new.w;
        }
        s1p = s1c; s1c = s1n;
        a2n = a2_new;

        // B2
        asm volatile("s_waitcnt lgkmcnt(0)" ::: "memory");
        __builtin_amdgcn_s_barrier();

        // ---------------- S2: smooth A2 at row a-3 ----------------
        float4 s2_new = z4;
        if (j >= 6) {
            const int s = a - 3;
            if (s >= 0 && s < H) {
                float4 v;
                v.x = a2p.x + 2.f * a2c.x + a2n.x;
                v.y = a2p.y + 2.f * a2c.y + a2n.y;
                v.z = a2p.z + 2.f * a2c.z + a2n.z;
                v.w = a2p.w + 2.f * a2c.w + a2n.w;
                float vL = __shfl_up(v.w, 1);
                float vR = __shfl_down(v.x, 1);
                if (isL) vL = domL ? 0.f
                    : (eA2[sl_m4][wv - 1][1] + 2.f * eA2[sl_m3][wv - 1][1] + eA2[sl_m2][wv - 1][1]);
                if (isR) vR = domR ? 0.f
                    : (eA2[sl_m4][wv + 1][0] + 2.f * eA2[sl_m3][wv + 1][0] + eA2[sl_m2][wv + 1][0]);
                s2_new.x = (vL  + 2.f * v.x + v.y) * 0.0625f * m4.x;
                s2_new.y = (v.x + 2.f * v.y + v.z) * 0.0625f * m4.y;
                s2_new.z = (v.y + 2.f * v.z + v.w) * 0.0625f * m4.z;
                s2_new.w = (v.z + 2.f * v.w + vR ) * 0.0625f * m4.w;
            }
            if (isL) eS2[sl_m3][wv][0] = s2_new.x;
            if (isR) eS2[sl_m3][wv][1] = s2_new.w;
        }
        a2p = a2c; a2c = a2n;
        s2n = s2_new;

        // ---------------- A3: advect S2 at row a-4 ----------------
        float4 a3_new = z4;
        if (j >= 8) {
            const int p = a - 4;
            if (p >= 0 && p < H) {
                const float ix  = coef[p];
                const float sxh = 0.5f * ix;
                float cL = __shfl_up(s2c.w, 1);
                float cR = __shfl_down(s2c.x, 1);
                float sxx = sxh, sxw = sxh;
                if (isL) { if (domL) { cL = s2c.x; sxx = ix; } else cL = eS2[sl_m4][wv - 1][1]; }
                if (isR) { if (domR) { cR = s2c.w; sxw = ix; } else cR = eS2[sl_m4][wv + 1][0]; }
                const float4 yl = (p == 0)     ? s2c : s2p;
                const float4 yh = (p == H - 1) ? s2c : s2n;
                const float sy  = (p == 0 || p == H - 1) ? inv_dy : 0.5f * inv_dy;
                a3_new.x = s2c.x + DT_S * (-(u5.x * ((s2c.y - cL  ) * sxx) + g5.x * ((yh.x - yl.x) * sy)) * m5.x);
                a3_new.y = s2c.y + DT_S * (-(u5.y * ((s2c.z - s2c.x) * sxh) + g5.y * ((yh.y - yl.y) * sy)) * m5.y);
                a3_new.z = s2c.z + DT_S * (-(u5.z * ((s2c.w - s2c.y) * sxh) + g5.z * ((yh.z - yl.z) * sy)) * m5.z);
                a3_new.w = s2c.w + DT_S * (-(u5.w * ((cR   - s2c.z) * sxw) + g5.w * ((yh.w - yl.w) * sy)) * m5.w);
            }
            if (isL) eA3[sl_m4][wv][0] = a3_new.x;
            if (isR) eA3[sl_m4][wv][1] = a3_new.w;
        }
        s2p = s2c; s2c = s2n;
        a3n = a3_new;

        // B3
        asm volatile("s_waitcnt lgkmcnt(0)" ::: "memory");
        __builtin_amdgcn_s_barrier();

        // ---------------- S3: smooth A3 at row a-5 ----------------
        float4 s3_new = z4;
        if (j >= 10) {
            const int s = a - 5;
            if (s >= 0 && s < H) {
                float4 v;
                v.x = a3p.x + 2.f * a3c.x + a3n.x;
                v.y = a3p.y + 2.f * a3c.y + a3n.y;
                v.z = a3p.z + 2.f * a3c.z + a3n.z;
                v.w = a3p.w + 2.f * a3c.w + a3n.w;
                float vL = __shfl_up(v.w, 1);
                float vR = __shfl_down(v.x, 1);
                if (isL) vL = domL ? 0.f
                    : (eA3[sl_m6][wv - 1][1] + 2.f * eA3[sl_m5][wv - 1][1] + eA3[sl_m4][wv - 1][1]);
                if (isR) vR = domR ? 0.f
                    : (eA3[sl_m6][wv + 1][0] + 2.f * eA3[sl_m5][wv + 1][0] + eA3[sl_m4][wv + 1][0]);
                s3_new.x = (vL  + 2.f * v.x + v.y) * 0.0625f * m6.x;
                s3_new.y = (v.x + 2.f * v.y + v.z) * 0.0625f * m6.y;
                s3_new.z = (v.y + 2.f * v.z + v.w) * 0.0625f * m6.z;
                s3_new.w = (v.z + 2.f * v.w + vR ) * 0.0625f * m6.w;
            }
            if (isL) eS3[sl_m5][wv][0] = s3_new.x;
            if (isR) eS3[sl_m5][wv][1] = s3_new.w;
        }
        a3p = a3c; a3c = a3n;
        s3n = s3_new;

        // ---------------- A4: advect S3 at row a-6 ----------------
        float4 a4_new = z4;
        if (j >= 12) {
            const int p = a - 6;
            if (p >= 0 && p < H) {
                const float ix  = coef[p];
                const float sxh = 0.5f * ix;
                float cL = __shfl_up(s3c.w, 1);
                float cR = __shfl_down(s3c.x, 1);
                float sxx = sxh, sxw = sxh;
                if (isL) { if (domL) { cL = s3c.x; sxx = ix; } else cL = eS3[sl_m6][wv - 1][1]; }
                if (isR) { if (domR) { cR = s3c.w; sxw = ix; } else cR = eS3[sl_m6][wv + 1][0]; }
                const float4 yl = (p == 0)     ? s3c : s3p;
                const float4 yh = (p == H - 1) ? s3c : s3n;
                const float sy  = (p == 0 || p == H - 1) ? inv_dy : 0.5f * inv_dy;
                a4_new.x = s3c.x + DT_S * (-(u7.x * ((s3c.y - cL  ) * sxx) + g7.x * ((yh.x - yl.x) * sy)) * m7.x);
                a4_new.y = s3c.y + DT_S * (-(u7.y * ((s3c.z - s3c.x) * sxh) + g7.y * ((yh.y - yl.y) * sy)) * m7.y);
                a4_new.z = s3c.z + DT_S * (-(u7.z * ((s3c.w - s3c.y) * sxh) + g7.z * ((yh.z - yl.z) * sy)) * m7.z);
                a4_new.w = s3c.w + DT_S * (-(u7.w * ((cR   - s3c.z) * sxw) + g7.w * ((yh.w - yl.w) * sy)) * m7.w);
            }
            if (isL) eA4[sl_m6][wv][0] = a4_new.x;
            if (isR) eA4[sl_m6][wv][1] = a4_new.w;
        }
        s3p = s3c; s3c = s3n;
        a4n = a4_new;

        // B4
        asm volatile("s_waitcnt lgkmcnt(0)" ::: "memory");
        __builtin_amdgcn_s_barrier();

        // ---------------- out: smooth A4 at row a-7 ----------------
        if (j >= 14) {
            const int r = a - 7;                 // in [h0, h0+SH4)
            if (r < H) {
                float4 v;
                v.x = a4p.x + 2.f * a4c.x + a4n.x;
                v.y = a4p.y + 2.f * a4c.y + a4n.y;
                v.z = a4p.z + 2.f * a4c.z + a4n.z;
                v.w = a4p.w + 2.f * a4c.w + a4n.w;
                float vL = __shfl_up(v.w, 1);
                float vR = __shfl_down(v.x, 1);
                if (isL) vL = domL ? 0.f
                    : (eA4[sl_m8][wv - 1][1] + 2.f * eA4[sl_m7][wv - 1][1] + eA4[sl_m6][wv - 1][1]);
                if (isR) vR = domR ? 0.f
                    : (eA4[sl_m8][wv + 1][0] + 2.f * eA4[sl_m7][wv + 1][0] + eA4[sl_m6][wv + 1][0]);
                float4 o;
                o.x = (vL  + 2.f * v.x + v.y) * 0.0625f * m8.x;
                o.y = (v.x + 2.f * v.y + v.z) * 0.0625f * m8.y;
                o.z = (v.y + 2.f * v.z + v.w) * 0.0625f * m8.z;
                o.w = (v.z + 2.f * v.w + vR ) * 0.0625f * m8.w;
                *(float4*)(To + (size_t)r * W + gw) = o;
            }
        }
        a4p = a4c; a4c = a4n;
    }
}

// --------- legacy single-step stream kernel (fallback, W % 256 == 0) -------
__global__ __launch_bounds__(256, 4)
void stream_kernel(const float* __restrict__ Tin, const float* __restrict__ ug,
                   const float* __restrict__ vg, const float* __restrict__ mask,
                   const float* __restrict__ coef, float* __restrict__ Tout,
                   int H, int W) {
    const int lane = threadIdx.x & 63;
    const int wv   = threadIdx.x >> 6;
    const int ws   = blockIdx.x * WPW;
    const int hs   = (blockIdx.y * 4 + wv) * STRIP;
    const int b    = blockIdx.z;
    if (hs >= H) return;
    const size_t plane = (size_t)H * W;
    const float* __restrict__ Tb  = Tin + b * plane;
    const float* __restrict__ ugb = ug  + b * plane;
    const float* __restrict__ vgb = vg  + b * plane;
    float* __restrict__ To = Tout + b * plane;
    const float inv_dy = coef[H];
    const bool atL = (ws == 0);
    const bool atR = (ws + WPW >= W);
    const bool isL = (lane == 0);
    const bool isR = (lane == 63);
    const int gw = ws + 4 * lane;

    auto clampr = [&](int r) { return min(max(r, 0), H - 1); };
    auto ldT = [&](int r) -> float4 {
        return *(const float4*)(Tb + (size_t)clampr(r) * W + gw);
    };
    auto ldL = [&](int r) -> float2 {
        float4 q = *(const float4*)(Tb + (size_t)clampr(r) * W + (ws - 4));
        return make_float2(q.z, q.w);
    };
    auto ldR = [&](int r) -> float2 {
        float4 q = *(const float4*)(Tb + (size_t)clampr(r) * W + (ws + WPW));
        return make_float2(q.x, q.y);
    };

    float4 tp, tc, tn;
    float  tLp_w = 0.f; float2 tLc = make_float2(0.f, 0.f), tLn = make_float2(0.f, 0.f);
    float  tRp_x = 0.f; float2 tRc = make_float2(0.f, 0.f), tRn = make_float2(0.f, 0.f);

    auto roll = [&](int rnext) {
        tp = tc; tc = tn; tn = ldT(rnext);
        if (!atL) { tLp_w = tLc.y; tLc = tLn; tLn = ldL(rnext); }
        if (!atR) { tRp_x = tRc.x; tRc = tRn; tRn = ldR(rnext); }
    };

    auto advrow = [&](int r, float4& a, float& aL, float& aR, float4& mOut) {
        if (r < 0 || r >= H) {
            a = make_float4(0.f, 0.f, 0.f, 0.f); aL = 0.f; aR = 0.f;
            mOut = make_float4(0.f, 0.f, 0.f, 0.f); return;
        }
        const size_t ro = (size_t)r * W;
        const float ix  = coef[r];
        const float sy  = (r == 0 || r == H - 1) ? inv_dy : 0.5f * inv_dy;
        const float sxh = 0.5f * ix;
        float4 u4 = *(const float4*)(ugb + ro + gw);
        float4 g4 = *(const float4*)(vgb + ro + gw);
        float4 m4 = *(const float4*)(mask + ro + gw);
        float cLw = __shfl_up(tc.w, 1);
        float cRx = __shfl_down(tc.x, 1);
        float sxx = sxh, sxw = sxh;
        if (isL) { if (atL) { cLw = tc.x; sxx = ix; } else { cLw = tLc.y; } }
        if (isR) { if (atR) { cRx = tc.w; sxw = ix; } else { cRx = tRc.x; } }
        a.x = tc.x + DT_S * (-(u4.x * ((tc.y - cLw) * sxx) + g4.x * ((tn.x - tp.x) * sy)) * m4.x);
        a.y = tc.y + DT_S * (-(u4.y * ((tc.z - tc.x) * sxh) + g4.y * ((tn.y - tp.y) * sy)) * m4.y);
        a.z = tc.z + DT_S * (-(u4.z * ((tc.w - tc.y) * sxh) + g4.z * ((tn.z - tp.z) * sy)) * m4.z);
        a.w = tc.w + DT_S * (-(u4.w * ((cRx - tc.z) * sxw) + g4.w * ((tn.w - tp.w) * sy)) * m4.w);
        if (!atL) {
            float uL = ((const float4*)(ugb + ro + (ws - 4)))->w;
            float gL = ((const float4*)(vgb + ro + (ws - 4)))->w;
            float mL = ((const float4*)(mask + ro + (ws - 4)))->w;
            aL = tLc.y + DT_S * (-(uL * ((tc.x - tLc.x) * sxh) + gL * ((tLn.y - tLp_w) * sy)) * mL);
        } else aL = 0.f;
        if (!atR) {
            float uR = ((const float4*)(ugb + ro + (ws + WPW)))->x;
            float gR = ((const float4*)(vgb + ro + (ws + WPW)))->x;
            float mR = ((const float4*)(mask + ro + (ws + WPW)))->x;
            aR = tRc.x + DT_S * (-(uR * ((tRc.y - tc.w) * sxh) + gR * ((tRn.x - tRp_x) * sy)) * mR);
        } else aR = 0.f;
        mOut = m4;
    };

    tp = ldT(hs - 2); tc = ldT(hs - 1); tn = ldT(hs);
    if (!atL) { float2 q = ldL(hs - 2); tLp_w = q.y; tLc = ldL(hs - 1); tLn = ldL(hs); }
    if (!atR) { float2 q = ldR(hs - 2); tRp_x = q.x; tRc = ldR(hs - 1); tRn = ldR(hs); }

    float4 ap, ac, an, mC, mN, mdum;
    float aLp, aLc, aLn, aRp, aRc, aRn;
    advrow(hs - 1, ap, aLp, aRp, mdum);
    roll(hs + 1);
    advrow(hs, ac, aLc, aRc, mC);

    #pragma unroll
    for (int i = 0; i < STRIP; ++i) {
        const int go = hs + i;
        roll(go + 2);
        advrow(go + 1, an, aLn, aRn, mN);
        if (go < H) {
            float4 v;
            v.x = ap.x + 2.f * ac.x + an.x;
            v.y = ap.y + 2.f * ac.y + an.y;
            v.z = ap.z + 2.f * ac.z + an.z;
            v.w = ap.w + 2.f * ac.w + an.w;
            float vL  = aLp + 2.f * aLc + aLn;
            float vR  = aRp + 2.f * aRc + aRn;
            float vLw = __shfl_up(v.w, 1);
            float vRx = __shfl_down(v.x, 1);
            if (isL) vLw = atL ? 0.f : vL;
            if (isR) vRx = atR ? 0.f : vR;
            float4 o;
            o.x = (vLw + 2.f * v.x + v.y) * 0.0625f * mC.x;
            o.y = (v.x + 2.f * v.y + v.z) * 0.0625f * mC.y;
            o.z = (v.y + 2.f * v.z + v.w) * 0.0625f * mC.z;
            o.w = (v.z + 2.f * v.w + vRx) * 0.0625f * mC.w;
            *(float4*)(To + (size_t)go * W + gw) = o;
        }
        ap = ac; ac = an;
        aLp = aLc; aLc = aLn; aRp = aRc; aRc = aRn;
        mC = mN;
    }
}

// ---------- generic fallback (round-1 LDS tile kernel, validated) ----------
constexpr int FTW = 64, FTH = 32;
constexpr int FSTW = FTW + 4, FSTH = FTH + 4;
constexpr int FMTW = FTW + 2, FMTH = FTH + 2;

__global__ __launch_bounds__(256)
void step_tile(const float* __restrict__ Tin, const float* __restrict__ ug,
               const float* __restrict__ vg, const float* __restrict__ mask,
               const float* __restrict__ coef, float* __restrict__ Tout,
               int H, int W) {
    __shared__ float sT[FSTH][FSTW];
    __shared__ float sM[FMTH][FMTW];
    const int tid = threadIdx.x;
    const int w0 = blockIdx.x * FTW;
    const int h0 = blockIdx.y * FTH;
    const int b  = blockIdx.z;
    const long plane = (long)H * W;
    const float* Tb  = Tin + b * plane;
    const float* ugb = ug  + b * plane;
    const float* vgb = vg  + b * plane;
    const float inv_dy = coef[H];

    for (int i = tid; i < FSTH * FSTW; i += NT) {
        int r = i / FSTW, c = i - r * FSTW;
        int gh = min(max(h0 - 2 + r, 0), H - 1);
        int gw = min(max(w0 - 2 + c, 0), W - 1);
        sT[r][c] = Tb[gh * W + gw];
    }
    __syncthreads();
    for (int i = tid; i < FMTH * FMTW; i += NT) {
        int r = i / FMTW, c = i - r * FMTW;
        int gh = h0 - 1 + r, gw = w0 - 1 + c;
        float v = 0.0f;
        if (gh >= 0 && gh < H && gw >= 0 && gw < W) {
            int sr = r + 1, sc = c + 1;
            float ndy = sT[sr + 1][sc] - sT[sr - 1][sc];
            float ndx = sT[sr][sc + 1] - sT[sr][sc - 1];
            float sy  = (gh == 0 || gh == H - 1) ? inv_dy : 0.5f * inv_dy;
            float ix  = coef[gh];
            float sx  = (gw == 0 || gw == W - 1) ? ix : 0.5f * ix;
            int   gi  = gh * W + gw;
            float F   = -(ugb[gi] * (ndx * sx) + vgb[gi] * (ndy * sy)) * mask[gi];
            v = sT[sr][sc] + DT_S * F;
        }
        sM[r][c] = v;
    }
    __syncthreads();
    float* To = Tout + b * plane;
    for (int i = tid; i < FTH * FTW; i += NT) {
        int r = i >> 6, c = i & (FTW - 1);
        int gh = h0 + r, gw = w0 + c;
        if (gh < H && gw < W) {
            int sr = r + 1, sc = c + 1;
            float s = (sM[sr-1][sc-1] + sM[sr-1][sc+1] + sM[sr+1][sc-1] + sM[sr+1][sc+1])
                    + 2.0f * (sM[sr-1][sc] + sM[sr+1][sc] + sM[sr][sc-1] + sM[sr][sc+1])
                    + 4.0f * sM[sr][sc];
            To[gh * W + gw] = s * 0.0625f * mask[gh * W + gw];
        }
    }
}

extern "C" void kernel_launch(void* const* d_in, const int* in_sizes, int n_in,
                              void* d_out, int out_size, void* d_ws, size_t ws_size,
                              hipStream_t stream) {
    const float* T0   = (const float*)d_in[0];
    const float* ug   = (const float*)d_in[1];
    const float* vg   = (const float*)d_in[2];
    const float* lat  = (const float*)d_in[3];
    const float* lon  = (const float*)d_in[4];
    const float* mask = (const float*)d_in[5];

    const int H = in_sizes[3];
    const int W = in_sizes[4];
    const int B = in_sizes[0] / (H * W);

    float* out  = (float*)d_out;
    float* ping = (float*)d_ws;                 // B*H*W floats
    float* coef = ping + (size_t)B * H * W;     // H+1 floats: 1/dx[h], then 1/dy

    prep_kernel<<<dim3((H + NT - 1) / NT), dim3(NT), 0, stream>>>(lat, lon, coef, H);

    const int STEPS = 48;

    if (W == FWAVES * 256) {
        // fused 4-step path: 12 launches, each = 4 simulated steps
        dim3 gridF4((H + SH4 - 1) / SH4, B);
        const int NLAUNCH = STEPS / 4;          // 12, even -> last dst == out
        for (int i = 0; i < NLAUNCH; ++i) {
            const float* src = (i == 0) ? T0 : ((i & 1) ? ping : out);
            float*       dst = (i & 1) ? out : ping;
            fused4_kernel<<<gridF4, dim3(NT), 0, stream>>>(src, ug, vg, mask, coef, dst, H, W);
        }
    } else {
        const bool fast = (W % WPW) == 0;
        dim3 gridS(W / (fast ? WPW : 1), (H + 4 * STRIP - 1) / (4 * STRIP), B);
        dim3 gridF((W + FTW - 1) / FTW, (H + FTH - 1) / FTH, B);
        for (int i = 0; i < STEPS; ++i) {
            const float* src = (i == 0) ? T0 : ((i & 1) ? ping : out);
            float*       dst = (i & 1) ? out : ping;
            if (fast)
                stream_kernel<<<gridS, dim3(NT), 0, stream>>>(src, ug, vg, mask, coef, dst, H, W);
            else
                step_tile<<<gridF, dim3(NT), 0, stream>>>(src, ug, vg, mask, coef, dst, H, W);
        }
    }
}

// Round 9
// 1606.794 us; speedup vs baseline: 1.2547x; 1.0060x over previous
//
#include <hip/hip_runtime.h>

// Ocean advection + 3x3 binomial smoothing, 48 steps, fp32.
//
// TEMPORAL FUSION x4: each kernel performs FOUR advect+smooth steps with all
// intermediates in registers. 12 dispatches. Unique traffic per step ~1/4.
//
// ROUND-9 CHANGE: __launch_bounds__(256,1) -> __launch_bounds__(256).
// Evidence across rounds 3/6/7/8: the 2nd launch_bounds arg acts as BOTH a
// compiler VGPR budget (256/N: 64@N=4, 128@N=2) AND a hardware waves-per-EU
// MAX (round 6: VGPR=120 yet pinned at 2 blocks/CU; round 8: (256,1) pinned
// at 1 block/CU = 134us despite VGPR=152 fitting 2). Dropping the 2nd arg
// removes the occupancy cap while keeping the large register budget ->
// VGPR ~152 (alloc quantum 256) -> 2 waves/SIMD -> 2 blocks/CU -> the whole
// 512-block grid is one co-resident generation.
// Tripwires: WRITE_SIZE must stay 32768 KB (no spill); VGPR must be <=256;
// OccupancyPercent should recover to ~22%.
//
// fused4_kernel (1-row-per-stage skew, 4 lgkm-only barriers/iter):
//   iteration j (a = h0-7+j), full unroll, ring slot = row & 7 (h0%8==0):
//     loads: T row a+2, ug/vg row a+1, mask row a+1 (1 iter ahead;
//            u/g FIFO depth 8, m depth 9 - reused across stages)
//     A1 = advect(T)   @ a    -> publish; B1
//     S1 = smooth(A1)  @ a-1  -> publish
//     A2 = advect(S1)  @ a-2  -> publish; B2
//     S2 = smooth(A2)  @ a-3  -> publish
//     A3 = advect(S2)  @ a-4  -> publish; B3
//     S3 = smooth(A3)  @ a-5  -> publish
//     A4 = advect(S3)  @ a-6  -> publish; B4
//     out= smooth(A4)  @ a-7  -> global store
//   Cross-wave x-halo via LDS edge rings (8-row ring x wave x {first,last}
//   col); every cross-wave read is >=1 barrier after its publish; ring depth
//   8 => WAR distance >=6 barriers. Raw s_barrier + lgkmcnt(0) only ->
//   global prefetches stay in flight.

#define DEG2RAD 0.017453292519943295f
#define R_EARTH 6371000.0f
#define DT_S 600.0f

constexpr int NT    = 256;   // threads per block
constexpr int STRIP = 8;     // legacy stream kernel: rows per wave
constexpr int WPW   = 256;   // legacy stream kernel: cols per wave

__global__ __launch_bounds__(256)
void prep_kernel(const float* __restrict__ lat, const float* __restrict__ lon,
                 float* __restrict__ coef, int H) {
    int h = blockIdx.x * blockDim.x + threadIdx.x;
    if (h < H) {
        float dlon = lon[1] - lon[0];
        coef[h] = 1.0f / (R_EARTH * DEG2RAD * dlon * cosf(lat[h] * DEG2RAD));
    }
    if (h == 0) {
        float dlat = lat[1] - lat[0];
        coef[H] = 1.0f / (R_EARTH * DEG2RAD * dlat);
    }
}

// ------------------------- fused 4-step kernel -----------------------------
constexpr int FWAVES = 4;    // waves per block, FWAVES*256 must == W
constexpr int SH4    = 16;   // output rows per block chunk (SH4 % 8 == 0!)
constexpr int NITER4 = SH4 + 14;

__global__ __launch_bounds__(256)
void fused4_kernel(const float* __restrict__ Tin, const float* __restrict__ ug,
                   const float* __restrict__ vg, const float* __restrict__ mask,
                   const float* __restrict__ coef, float* __restrict__ Tout,
                   int H, int W) {
    const int lane = threadIdx.x & 63;
    const int wv   = threadIdx.x >> 6;
    const int h0   = blockIdx.x * SH4;
    const int b    = blockIdx.y;
    const int gw   = (wv << 8) + (lane << 2);
    const size_t plane = (size_t)H * W;
    const float* __restrict__ Tb  = Tin + b * plane;
    const float* __restrict__ ugb = ug  + b * plane;
    const float* __restrict__ vgb = vg  + b * plane;
    float* __restrict__ To = Tout + b * plane;
    const float inv_dy = coef[H];
    const bool isL = (lane == 0), isR = (lane == 63);
    const bool domL = (wv == 0), domR = (wv == FWAVES - 1);

    // edge rings: [row & 7][wave][0 = first col, 1 = last col]
    __shared__ float eT [8][FWAVES][2];
    __shared__ float eA1[8][FWAVES][2];
    __shared__ float eS1[8][FWAVES][2];
    __shared__ float eA2[8][FWAVES][2];
    __shared__ float eS2[8][FWAVES][2];
    __shared__ float eA3[8][FWAVES][2];
    __shared__ float eS3[8][FWAVES][2];
    __shared__ float eA4[8][FWAVES][2];

    auto rowc = [&](int r) { return min(max(r, 0), H - 1); };
    auto ld4 = [&](const float* __restrict__ p, int r) -> float4 {
        return *(const float4*)(p + (size_t)rowc(r) * W + gw);
    };
    const float4 z4 = make_float4(0.f, 0.f, 0.f, 0.f);

    // ---- warm-up: after the j=0 roll, t0..t3 = rows a-1..a+2 (a = h0-7) ----
    float4 t0 = z4;
    float4 t1 = ld4(Tb, h0 - 8);
    float4 t2 = ld4(Tb, h0 - 7);
    float4 t3 = ld4(Tb, h0 - 6);
    // FIFOs: slot k holds row (a+1-k) after the roll
    float4 u0 = ld4(ugb, h0 - 7), u1 = z4, u2 = z4, u3 = z4, u4 = z4, u5 = z4, u6 = z4, u7 = z4;
    float4 g0 = ld4(vgb, h0 - 7), g1 = z4, g2 = z4, g3 = z4, g4 = z4, g5 = z4, g6 = z4, g7 = z4;
    float4 m0 = ld4(mask, h0 - 7), m1 = z4, m2 = z4, m3 = z4, m4 = z4, m5 = z4, m6 = z4, m7 = z4, m8 = z4;
    float4 a1p = z4, a1c = z4, a1n = z4;
    float4 s1p = z4, s1c = z4, s1n = z4;
    float4 a2p = z4, a2c = z4, a2n = z4;
    float4 s2p = z4, s2c = z4, s2n = z4;
    float4 a3p = z4, a3c = z4, a3n = z4;
    float4 s3p = z4, s3c = z4, s3n = z4;
    float4 a4p = z4, a4c = z4, a4n = z4;

    // pre-publish eT rows h0-7 (slot 1) and h0-6 (slot 2)  [h0 % 8 == 0]
    if (isL) { eT[1][wv][0] = t2.x; eT[2][wv][0] = t3.x; }
    if (isR) { eT[1][wv][1] = t2.w; eT[2][wv][1] = t3.w; }
    asm volatile("s_waitcnt lgkmcnt(0)" ::: "memory");
    __builtin_amdgcn_s_barrier();

    #pragma unroll
    for (int j = 0; j < NITER4; ++j) {
        const int a = h0 - 7 + j;               // A1 row; a & 7 == (j+1) & 7
        // ring slots for rows a+1 .. a-8 (row r -> r & 7):
        const int sl_a1p = (j + 2) & 7;         // row a+1
        const int sl_a   = (j + 1) & 7;         // row a
        const int sl_m1  = (j + 0) & 7;         // row a-1
        const int sl_m2  = (j + 7) & 7;         // row a-2
        const int sl_m3  = (j + 6) & 7;         // row a-3
        const int sl_m4  = (j + 5) & 7;         // row a-4
        const int sl_m5  = (j + 4) & 7;         // row a-5
        const int sl_m6  = (j + 3) & 7;         // row a-6
        const int sl_m7  = (j + 2) & 7;         // row a-7 (aliases a+1; diff rings)
        const int sl_m8  = (j + 1) & 7;         // row a-8 (aliases a;   diff rings)

        // ---- roll chains/FIFOs, issue loads (consumed next iter) ----
        t0 = t1; t1 = t2; t2 = t3; t3 = ld4(Tb, a + 2);
        u7 = u6; u6 = u5; u5 = u4; u4 = u3; u3 = u2; u2 = u1; u1 = u0; u0 = ld4(ugb, a + 1);
        g7 = g6; g6 = g5; g5 = g4; g4 = g3; g3 = g2; g2 = g1; g1 = g0; g0 = ld4(vgb, a + 1);
        m8 = m7; m7 = m6; m6 = m5; m5 = m4; m4 = m3; m3 = m2; m2 = m1; m1 = m0; m0 = ld4(mask, a + 1);

        // publish T edges for row a+1 (t2: load completed last iteration)
        if (isL) eT[sl_a1p][wv][0] = t2.x;
        if (isR) eT[sl_a1p][wv][1] = t2.w;

        // ---------------- A1: advect T at row a ----------------
        float4 a1_new = z4;
        if (a >= 0 && a < H) {
            const float ix  = coef[a];
            const float sy  = (a == 0 || a == H - 1) ? inv_dy : 0.5f * inv_dy;
            const float sxh = 0.5f * ix;
            float cL = __shfl_up(t1.w, 1);
            float cR = __shfl_down(t1.x, 1);
            float sxx = sxh, sxw = sxh;
            if (isL) { if (domL) { cL = t1.x; sxx = ix; } else cL = eT[sl_a][wv - 1][1]; }
            if (isR) { if (domR) { cR = t1.w; sxw = ix; } else cR = eT[sl_a][wv + 1][0]; }
            a1_new.x = t1.x + DT_S * (-(u1.x * ((t1.y - cL ) * sxx) + g1.x * ((t2.x - t0.x) * sy)) * m1.x);
            a1_new.y = t1.y + DT_S * (-(u1.y * ((t1.z - t1.x) * sxh) + g1.y * ((t2.y - t0.y) * sy)) * m1.y);
            a1_new.z = t1.z + DT_S * (-(u1.z * ((t1.w - t1.y) * sxh) + g1.z * ((t2.z - t0.z) * sy)) * m1.z);
            a1_new.w = t1.w + DT_S * (-(u1.w * ((cR  - t1.z) * sxw) + g1.w * ((t2.w - t0.w) * sy)) * m1.w);
        }
        if (isL) eA1[sl_a][wv][0] = a1_new.x;
        if (isR) eA1[sl_a][wv][1] = a1_new.w;
        a1n = a1_new;

        // B1 (lgkm-only: global prefetches stay in flight)
        asm volatile("s_waitcnt lgkmcnt(0)" ::: "memory");
        __builtin_amdgcn_s_barrier();

        // ---------------- S1: smooth A1 at row a-1 ----------------
        float4 s1_new = z4;
        if (j >= 2) {
            const int s = a - 1;
            if (s >= 0 && s < H) {
                float4 v;
                v.x = a1p.x + 2.f * a1c.x + a1n.x;
                v.y = a1p.y + 2.f * a1c.y + a1n.y;
                v.z = a1p.z + 2.f * a1c.z + a1n.z;
                v.w = a1p.w + 2.f * a1c.w + a1n.w;
                float vL = __shfl_up(v.w, 1);
                float vR = __shfl_down(v.x, 1);
                if (isL) vL = domL ? 0.f
                    : (eA1[sl_m2][wv - 1][1] + 2.f * eA1[sl_m1][wv - 1][1] + eA1[sl_a][wv - 1][1]);
                if (isR) vR = domR ? 0.f
                    : (eA1[sl_m2][wv + 1][0] + 2.f * eA1[sl_m1][wv + 1][0] + eA1[sl_a][wv + 1][0]);
                s1_new.x = (vL  + 2.f * v.x + v.y) * 0.0625f * m2.x;
                s1_new.y = (v.x + 2.f * v.y + v.z) * 0.0625f * m2.y;
                s1_new.z = (v.y + 2.f * v.z + v.w) * 0.0625f * m2.z;
                s1_new.w = (v.z + 2.f * v.w + vR ) * 0.0625f * m2.w;
            }
            if (isL) eS1[sl_m1][wv][0] = s1_new.x;
            if (isR) eS1[sl_m1][wv][1] = s1_new.w;
        }
        a1p = a1c; a1c = a1n;
        s1n = s1_new;

        // ---------------- A2: advect S1 at row a-2 ----------------
        float4 a2_new = z4;
        if (j >= 4) {
            const int q = a - 2;
            if (q >= 0 && q < H) {
                const float ix  = coef[q];
                const float sxh = 0.5f * ix;
                float cL = __shfl_up(s1c.w, 1);
                float cR = __shfl_down(s1c.x, 1);
                float sxx = sxh, sxw = sxh;
                if (isL) { if (domL) { cL = s1c.x; sxx = ix; } else cL = eS1[sl_m2][wv - 1][1]; }
                if (isR) { if (domR) { cR = s1c.w; sxw = ix; } else cR = eS1[sl_m2][wv + 1][0]; }
                const float4 yl = (q == 0)     ? s1c : s1p;
                const float4 yh = (q == H - 1) ? s1c : s1n;
                const float sy  = (q == 0 || q == H - 1) ? inv_dy : 0.5f * inv_dy;
                a2_new.x = s1c.x + DT_S * (-(u3.x * ((s1c.y - cL  ) * sxx) + g3.x * ((yh.x - yl.x) * sy)) * m3.x);
                a2_new.y = s1c.y + DT_S * (-(u3.y * ((s1c.z - s1c.x) * sxh) + g3.y * ((yh.y - yl.y) * sy)) * m3.y);
                a2_new.z = s1c.z + DT_S * (-(u3.z * ((s1c.w - s1c.y) * sxh) + g3.z * ((yh.z - yl.z) * sy)) * m3.z);
                a2_new.w = s1c.w + DT_S * (-(u3.w * ((cR   - s1c.z) * sxw) + g3.w * ((yh.w - yl.w) * sy)) * m3.w);
            }
            if (isL) eA2[sl_m2][wv][0] = a2_new.x;
            if (isR) eA2[sl_m2][wv][1] = a2_new.w;
        }
        s1p = s1c; s1c = s1n;
        a2n = a2_new;

        // B2
        asm volatile("s_waitcnt lgkmcnt(0)" ::: "memory");
        __builtin_amdgcn_s_barrier();

        // ---------------- S2: smooth A2 at row a-3 ----------------
        float4 s2_new = z4;
        if (j >= 6) {
            const int s = a - 3;
            if (s >= 0 && s < H) {
                float4 v;
                v.x = a2p.x + 2.f * a2c.x + a2n.x;
                v.y = a2p.y + 2.f * a2c.y + a2n.y;
                v.z = a2p.z + 2.f * a2c.z + a2n.z;
                v.w = a2p.w + 2.f * a2c.w + a2n.w;
                float vL = __shfl_up(v.w, 1);
                float vR = __shfl_down(v.x, 1);
                if (isL) vL = domL ? 0.f
                    : (eA2[sl_m4][wv - 1][1] + 2.f * eA2[sl_m3][wv - 1][1] + eA2[sl_m2][wv - 1][1]);
                if (isR) vR = domR ? 0.f
                    : (eA2[sl_m4][wv + 1][0] + 2.f * eA2[sl_m3][wv + 1][0] + eA2[sl_m2][wv + 1][0]);
                s2_new.x = (vL  + 2.f * v.x + v.y) * 0.0625f * m4.x;
                s2_new.y = (v.x + 2.f * v.y + v.z) * 0.0625f * m4.y;
                s2_new.z = (v.y + 2.f * v.z + v.w) * 0.0625f * m4.z;
                s2_new.w = (v.z + 2.f * v.w + vR ) * 0.0625f * m4.w;
            }
            if (isL) eS2[sl_m3][wv][0] = s2_new.x;
            if (isR) eS2[sl_m3][wv][1] = s2_new.w;
        }
        a2p = a2c; a2c = a2n;
        s2n = s2_new;

        // ---------------- A3: advect S2 at row a-4 ----------------
        float4 a3_new = z4;
        if (j >= 8) {
            const int p = a - 4;
            if (p >= 0 && p < H) {
                const float ix  = coef[p];
                const float sxh = 0.5f * ix;
                float cL = __shfl_up(s2c.w, 1);
                float cR = __shfl_down(s2c.x, 1);
                float sxx = sxh, sxw = sxh;
                if (isL) { if (domL) { cL = s2c.x; sxx = ix; } else cL = eS2[sl_m4][wv - 1][1]; }
                if (isR) { if (domR) { cR = s2c.w; sxw = ix; } else cR = eS2[sl_m4][wv + 1][0]; }
                const float4 yl = (p == 0)     ? s2c : s2p;
                const float4 yh = (p == H - 1) ? s2c : s2n;
                const float sy  = (p == 0 || p == H - 1) ? inv_dy : 0.5f * inv_dy;
                a3_new.x = s2c.x + DT_S * (-(u5.x * ((s2c.y - cL  ) * sxx) + g5.x * ((yh.x - yl.x) * sy)) * m5.x);
                a3_new.y = s2c.y + DT_S * (-(u5.y * ((s2c.z - s2c.x) * sxh) + g5.y * ((yh.y - yl.y) * sy)) * m5.y);
                a3_new.z = s2c.z + DT_S * (-(u5.z * ((s2c.w - s2c.y) * sxh) + g5.z * ((yh.z - yl.z) * sy)) * m5.z);
                a3_new.w = s2c.w + DT_S * (-(u5.w * ((cR   - s2c.z) * sxw) + g5.w * ((yh.w - yl.w) * sy)) * m5.w);
            }
            if (isL) eA3[sl_m4][wv][0] = a3_new.x;
            if (isR) eA3[sl_m4][wv][1] = a3_new.w;
        }
        s2p = s2c; s2c = s2n;
        a3n = a3_new;

        // B3
        asm volatile("s_waitcnt lgkmcnt(0)" ::: "memory");
        __builtin_amdgcn_s_barrier();

        // ---------------- S3: smooth A3 at row a-5 ----------------
        float4 s3_new = z4;
        if (j >= 10) {
            const int s = a - 5;
            if (s >= 0 && s < H) {
                float4 v;
                v.x = a3p.x + 2.f * a3c.x + a3n.x;
                v.y = a3p.y + 2.f * a3c.y + a3n.y;
                v.z = a3p.z + 2.f * a3c.z + a3n.z;
                v.w = a3p.w + 2.f * a3c.w + a3n.w;
                float vL = __shfl_up(v.w, 1);
                float vR = __shfl_down(v.x, 1);
                if (isL) vL = domL ? 0.f
                    : (eA3[sl_m6][wv - 1][1] + 2.f * eA3[sl_m5][wv - 1][1] + eA3[sl_m4][wv - 1][1]);
                if (isR) vR = domR ? 0.f
                    : (eA3[sl_m6][wv + 1][0] + 2.f * eA3[sl_m5][wv + 1][0] + eA3[sl_m4][wv + 1][0]);
                s3_new.x = (vL  + 2.f * v.x + v.y) * 0.0625f * m6.x;
                s3_new.y = (v.x + 2.f * v.y + v.z) * 0.0625f * m6.y;
                s3_new.z = (v.y + 2.f * v.z + v.w) * 0.0625f * m6.z;
                s3_new.w = (v.z + 2.f * v.w + vR ) * 0.0625f * m6.w;
            }
            if (isL) eS3[sl_m5][wv][0] = s3_new.x;
            if (isR) eS3[sl_m5][wv][1] = s3_new.w;
        }
        a3p = a3c; a3c = a3n;
        s3n = s3_new;

        // ---------------- A4: advect S3 at row a-6 ----------------
        float4 a4_new = z4;
        if (j >= 12) {
            const int p = a - 6;
            if (p >= 0 && p < H) {
                const float ix  = coef[p];
                const float sxh = 0.5f * ix;
                float cL = __shfl_up(s3c.w, 1);
                float cR = __shfl_down(s3c.x, 1);
                float sxx = sxh, sxw = sxh;
                if (isL) { if (domL) { cL = s3c.x; sxx = ix; } else cL = eS3[sl_m6][wv - 1][1]; }
                if (isR) { if (domR) { cR = s3c.w; sxw = ix; } else cR = eS3[sl_m6][wv + 1][0]; }
                const float4 yl = (p == 0)     ? s3c : s3p;
                const float4 yh = (p == H - 1) ? s3c : s3n;
                const float sy  = (p == 0 || p == H - 1) ? inv_dy : 0.5f * inv_dy;
                a4_new.x = s3c.x + DT_S * (-(u7.x * ((s3c.y - cL  ) * sxx) + g7.x * ((yh.x - yl.x) * sy)) * m7.x);
                a4_new.y = s3c.y + DT_S * (-(u7.y * ((s3c.z - s3c.x) * sxh) + g7.y * ((yh.y - yl.y) * sy)) * m7.y);
                a4_new.z = s3c.z + DT_S * (-(u7.z * ((s3c.w - s3c.y) * sxh) + g7.z * ((yh.z - yl.z) * sy)) * m7.z);
                a4_new.w = s3c.w + DT_S * (-(u7.w * ((cR   - s3c.z) * sxw) + g7.w * ((yh.w - yl.w) * sy)) * m7.w);
            }
            if (isL) eA4[sl_m6][wv][0] = a4_new.x;
            if (isR) eA4[sl_m6][wv][1] = a4_new.w;
        }
        s3p = s3c; s3c = s3n;
        a4n = a4_new;

        // B4
        asm volatile("s_waitcnt lgkmcnt(0)" ::: "memory");
        __builtin_amdgcn_s_barrier();

        // ---------------- out: smooth A4 at row a-7 ----------------
        if (j >= 14) {
            const int r = a - 7;                 // in [h0, h0+SH4)
            if (r < H) {
                float4 v;
                v.x = a4p.x + 2.f * a4c.x + a4n.x;
                v.y = a4p.y + 2.f * a4c.y + a4n.y;
                v.z = a4p.z + 2.f * a4c.z + a4n.z;
                v.w = a4p.w + 2.f * a4c.w + a4n.w;
                float vL = __shfl_up(v.w, 1);
                float vR = __shfl_down(v.x, 1);
                if (isL) vL = domL ? 0.f
                    : (eA4[sl_m8][wv - 1][1] + 2.f * eA4[sl_m7][wv - 1][1] + eA4[sl_m6][wv - 1][1]);
                if (isR) vR = domR ? 0.f
                    : (eA4[sl_m8][wv + 1][0] + 2.f * eA4[sl_m7][wv + 1][0] + eA4[sl_m6][wv + 1][0]);
                float4 o;
                o.x = (vL  + 2.f * v.x + v.y) * 0.0625f * m8.x;
                o.y = (v.x + 2.f * v.y + v.z) * 0.0625f * m8.y;
                o.z = (v.y + 2.f * v.z + v.w) * 0.0625f * m8.z;
                o.w = (v.z + 2.f * v.w + vR ) * 0.0625f * m8.w;
                *(float4*)(To + (size_t)r * W + gw) = o;
            }
        }
        a4p = a4c; a4c = a4n;
    }
}

// --------- legacy single-step stream kernel (fallback, W % 256 == 0) -------
__global__ __launch_bounds__(256, 4)
void stream_kernel(const float* __restrict__ Tin, const float* __restrict__ ug,
                   const float* __restrict__ vg, const float* __restrict__ mask,
                   const float* __restrict__ coef, float* __restrict__ Tout,
                   int H, int W) {
    const int lane = threadIdx.x & 63;
    const int wv   = threadIdx.x >> 6;
    const int ws   = blockIdx.x * WPW;
    const int hs   = (blockIdx.y * 4 + wv) * STRIP;
    const int b    = blockIdx.z;
    if (hs >= H) return;
    const size_t plane = (size_t)H * W;
    const float* __restrict__ Tb  = Tin + b * plane;
    const float* __restrict__ ugb = ug  + b * plane;
    const float* __restrict__ vgb = vg  + b * plane;
    float* __restrict__ To = Tout + b * plane;
    const float inv_dy = coef[H];
    const bool atL = (ws == 0);
    const bool atR = (ws + WPW >= W);
    const bool isL = (lane == 0);
    const bool isR = (lane == 63);
    const int gw = ws + 4 * lane;

    auto clampr = [&](int r) { return min(max(r, 0), H - 1); };
    auto ldT = [&](int r) -> float4 {
        return *(const float4*)(Tb + (size_t)clampr(r) * W + gw);
    };
    auto ldL = [&](int r) -> float2 {
        float4 q = *(const float4*)(Tb + (size_t)clampr(r) * W + (ws - 4));
        return make_float2(q.z, q.w);
    };
    auto ldR = [&](int r) -> float2 {
        float4 q = *(const float4*)(Tb + (size_t)clampr(r) * W + (ws + WPW));
        return make_float2(q.x, q.y);
    };

    float4 tp, tc, tn;
    float  tLp_w = 0.f; float2 tLc = make_float2(0.f, 0.f), tLn = make_float2(0.f, 0.f);
    float  tRp_x = 0.f; float2 tRc = make_float2(0.f, 0.f), tRn = make_float2(0.f, 0.f);

    auto roll = [&](int rnext) {
        tp = tc; tc = tn; tn = ldT(rnext);
        if (!atL) { tLp_w = tLc.y; tLc = tLn; tLn = ldL(rnext); }
        if (!atR) { tRp_x = tRc.x; tRc = tRn; tRn = ldR(rnext); }
    };

    auto advrow = [&](int r, float4& a, float& aL, float& aR, float4& mOut) {
        if (r < 0 || r >= H) {
            a = make_float4(0.f, 0.f, 0.f, 0.f); aL = 0.f; aR = 0.f;
            mOut = make_float4(0.f, 0.f, 0.f, 0.f); return;
        }
        const size_t ro = (size_t)r * W;
        const float ix  = coef[r];
        const float sy  = (r == 0 || r == H - 1) ? inv_dy : 0.5f * inv_dy;
        const float sxh = 0.5f * ix;
        float4 u4 = *(const float4*)(ugb + ro + gw);
        float4 g4 = *(const float4*)(vgb + ro + gw);
        float4 m4 = *(const float4*)(mask + ro + gw);
        float cLw = __shfl_up(tc.w, 1);
        float cRx = __shfl_down(tc.x, 1);
        float sxx = sxh, sxw = sxh;
        if (isL) { if (atL) { cLw = tc.x; sxx = ix; } else { cLw = tLc.y; } }
        if (isR) { if (atR) { cRx = tc.w; sxw = ix; } else { cRx = tRc.x; } }
        a.x = tc.x + DT_S * (-(u4.x * ((tc.y - cLw) * sxx) + g4.x * ((tn.x - tp.x) * sy)) * m4.x);
        a.y = tc.y + DT_S * (-(u4.y * ((tc.z - tc.x) * sxh) + g4.y * ((tn.y - tp.y) * sy)) * m4.y);
        a.z = tc.z + DT_S * (-(u4.z * ((tc.w - tc.y) * sxh) + g4.z * ((tn.z - tp.z) * sy)) * m4.z);
        a.w = tc.w + DT_S * (-(u4.w * ((cRx - tc.z) * sxw) + g4.w * ((tn.w - tp.w) * sy)) * m4.w);
        if (!atL) {
            float uL = ((const float4*)(ugb + ro + (ws - 4)))->w;
            float gL = ((const float4*)(vgb + ro + (ws - 4)))->w;
            float mL = ((const float4*)(mask + ro + (ws - 4)))->w;
            aL = tLc.y + DT_S * (-(uL * ((tc.x - tLc.x) * sxh) + gL * ((tLn.y - tLp_w) * sy)) * mL);
        } else aL = 0.f;
        if (!atR) {
            float uR = ((const float4*)(ugb + ro + (ws + WPW)))->x;
            float gR = ((const float4*)(vgb + ro + (ws + WPW)))->x;
            float mR = ((const float4*)(mask + ro + (ws + WPW)))->x;
            aR = tRc.x + DT_S * (-(uR * ((tRc.y - tc.w) * sxh) + gR * ((tRn.x - tRp_x) * sy)) * mR);
        } else aR = 0.f;
        mOut = m4;
    };

    tp = ldT(hs - 2); tc = ldT(hs - 1); tn = ldT(hs);
    if (!atL) { float2 q = ldL(hs - 2); tLp_w = q.y; tLc = ldL(hs - 1); tLn = ldL(hs); }
    if (!atR) { float2 q = ldR(hs - 2); tRp_x = q.x; tRc = ldR(hs - 1); tRn = ldR(hs); }

    float4 ap, ac, an, mC, mN, mdum;
    float aLp, aLc, aLn, aRp, aRc, aRn;
    advrow(hs - 1, ap, aLp, aRp, mdum);
    roll(hs + 1);
    advrow(hs, ac, aLc, aRc, mC);

    #pragma unroll
    for (int i = 0; i < STRIP; ++i) {
        const int go = hs + i;
        roll(go + 2);
        advrow(go + 1, an, aLn, aRn, mN);
        if (go < H) {
            float4 v;
            v.x = ap.x + 2.f * ac.x + an.x;
            v.y = ap.y + 2.f * ac.y + an.y;
            v.z = ap.z + 2.f * ac.z + an.z;
            v.w = ap.w + 2.f * ac.w + an.w;
            float vL  = aLp + 2.f * aLc + aLn;
            float vR  = aRp + 2.f * aRc + aRn;
            float vLw = __shfl_up(v.w, 1);
            float vRx = __shfl_down(v.x, 1);
            if (isL) vLw = atL ? 0.f : vL;
            if (isR) vRx = atR ? 0.f : vR;
            float4 o;
            o.x = (vLw + 2.f * v.x + v.y) * 0.0625f * mC.x;
            o.y = (v.x + 2.f * v.y + v.z) * 0.0625f * mC.y;
            o.z = (v.y + 2.f * v.z + v.w) * 0.0625f * mC.z;
            o.w = (v.z + 2.f * v.w + vRx) * 0.0625f * mC.w;
            *(float4*)(To + (size_t)go * W + gw) = o;
        }
        ap = ac; ac = an;
        aLp = aLc; aLc = aLn; aRp = aRc; aRc = aRn;
        mC = mN;
    }
}

// ---------- generic fallback (round-1 LDS tile kernel, validated) ----------
constexpr int FTW = 64, FTH = 32;
constexpr int FSTW = FTW + 4, FSTH = FTH + 4;
constexpr int FMTW = FTW + 2, FMTH = FTH + 2;

__global__ __launch_bounds__(256)
void step_tile(const float* __restrict__ Tin, const float* __restrict__ ug,
               const float* __restrict__ vg, const float* __restrict__ mask,
               const float* __restrict__ coef, float* __restrict__ Tout,
               int H, int W) {
    __shared__ float sT[FSTH][FSTW];
    __shared__ float sM[FMTH][FMTW];
    const int tid = threadIdx.x;
    const int w0 = blockIdx.x * FTW;
    const int h0 = blockIdx.y * FTH;
    const int b  = blockIdx.z;
    const long plane = (long)H * W;
    const float* Tb  = Tin + b * plane;
    const float* ugb = ug  + b * plane;
    const float* vgb = vg  + b * plane;
    const float inv_dy = coef[H];

    for (int i = tid; i < FSTH * FSTW; i += NT) {
        int r = i / FSTW, c = i - r * FSTW;
        int gh = min(max(h0 - 2 + r, 0), H - 1);
        int gw = min(max(w0 - 2 + c, 0), W - 1);
        sT[r][c] = Tb[gh * W + gw];
    }
    __syncthreads();
    for (int i = tid; i < FMTH * FMTW; i += NT) {
        int r = i / FMTW, c = i - r * FMTW;
        int gh = h0 - 1 + r, gw = w0 - 1 + c;
        float v = 0.0f;
        if (gh >= 0 && gh < H && gw >= 0 && gw < W) {
            int sr = r + 1, sc = c + 1;
            float ndy = sT[sr + 1][sc] - sT[sr - 1][sc];
            float ndx = sT[sr][sc + 1] - sT[sr][sc - 1];
            float sy  = (gh == 0 || gh == H - 1) ? inv_dy : 0.5f * inv_dy;
            float ix  = coef[gh];
            float sx  = (gw == 0 || gw == W - 1) ? ix : 0.5f * ix;
            int   gi  = gh * W + gw;
            float F   = -(ugb[gi] * (ndx * sx) + vgb[gi] * (ndy * sy)) * mask[gi];
            v = sT[sr][sc] + DT_S * F;
        }
        sM[r][c] = v;
    }
    __syncthreads();
    float* To = Tout + b * plane;
    for (int i = tid; i < FTH * FTW; i += NT) {
        int r = i >> 6, c = i & (FTW - 1);
        int gh = h0 + r, gw = w0 + c;
        if (gh < H && gw < W) {
            int sr = r + 1, sc = c + 1;
            float s = (sM[sr-1][sc-1] + sM[sr-1][sc+1] + sM[sr+1][sc-1] + sM[sr+1][sc+1])
                    + 2.0f * (sM[sr-1][sc] + sM[sr+1][sc] + sM[sr][sc-1] + sM[sr][sc+1])
                    + 4.0f * sM[sr][sc];
            To[gh * W + gw] = s * 0.0625f * mask[gh * W + gw];
        }
    }
}

extern "C" void kernel_launch(void* const* d_in, const int* in_sizes, int n_in,
                              void* d_out, int out_size, void* d_ws, size_t ws_size,
                              hipStream_t stream) {
    const float* T0   = (const float*)d_in[0];
    const float* ug   = (const float*)d_in[1];
    const float* vg   = (const float*)d_in[2];
    const float* lat  = (const float*)d_in[3];
    const float* lon  = (const float*)d_in[4];
    const float* mask = (const float*)d_in[5];

    const int H = in_sizes[3];
    const int W = in_sizes[4];
    const int B = in_sizes[0] / (H * W);

    float* out  = (float*)d_out;
    float* ping = (float*)d_ws;                 // B*H*W floats
    float* coef = ping + (size_t)B * H * W;     // H+1 floats: 1/dx[h], then 1/dy

    prep_kernel<<<dim3((H + NT - 1) / NT), dim3(NT), 0, stream>>>(lat, lon, coef, H);

    const int STEPS = 48;

    if (W == FWAVES * 256) {
        // fused 4-step path: 12 launches, each = 4 simulated steps
        dim3 gridF4((H + SH4 - 1) / SH4, B);
        const int NLAUNCH = STEPS / 4;          // 12, even -> last dst == out
        for (int i = 0; i < NLAUNCH; ++i) {
            const float* src = (i == 0) ? T0 : ((i & 1) ? ping : out);
            float*       dst = (i & 1) ? out : ping;
            fused4_kernel<<<gridF4, dim3(NT), 0, stream>>>(src, ug, vg, mask, coef, dst, H, W);
        }
    } else {
        const bool fast = (W % WPW) == 0;
        dim3 gridS(W / (fast ? WPW : 1), (H + 4 * STRIP - 1) / (4 * STRIP), B);
        dim3 gridF((W + FTW - 1) / FTW, (H + FTH - 1) / FTH, B);
        for (int i = 0; i < STEPS; ++i) {
            const float* src = (i == 0) ? T0 : ((i & 1) ? ping : out);
            float*       dst = (i & 1) ? out : ping;
            if (fast)
                stream_kernel<<<gridS, dim3(NT), 0, stream>>>(src, ug, vg, mask, coef, dst, H, W);
            else
                step_tile<<<gridF, dim3(NT), 0, stream>>>(src, ug, vg, mask, coef, dst, H, W);
        }
    }
}

// Round 10
// 1443.696 us; speedup vs baseline: 1.3964x; 1.1130x over previous
//
#include <hip/hip_runtime.h>

// Ocean advection + 3x3 binomial smoothing, 48 steps, fp32.
//
// ROUND-10: K=2 fusion at FOUR blocks/CU. Consolidated laws from rounds 1-9:
//   (1) occupancy: waves/SIMD = floor(256 / VGPR)  [<=64 -> 4 blocks/CU,
//       <=128 -> 2, >128 -> 1; launch_bounds 2nd arg only sets the compiler
//       VGPR budget 256/N, it never raised occupancy]
//   (2) per-block iteration time is a latency chain ~1.85us(K=2)/2.1(K=3)/
//       2.33(K=4), nearly independent of loads/barriers/co-residency
//   => throughput = blocks/CU / T_chain. Only big-win cell: K=2 @ 4 blocks/CU.
// K=2 minimal state = t-chain(16) + 3 stage chains(36) = 52 regs. Round-3's
// spill at cap-64 came from +40 regs of u/g/m FIFOs -> replaced with
// per-stage reloads (rows a-1..a-3 are L1-hot). Structure = round-3's
// correctness-verified 1-row-skew K=2 skeleton, SH=8, grid 1024 = one fully
// resident generation at 4 blocks/CU.
// Tripwires: VGPR=64; WRITE_SIZE must be 32768 KB EXACTLY (spill kills);
// OccupancyPercent ~40-48. If spilled -> revert to 872us K=3 champion.

#define DEG2RAD 0.017453292519943295f
#define R_EARTH 6371000.0f
#define DT_S 600.0f

constexpr int NT    = 256;   // threads per block
constexpr int STRIP = 8;     // legacy stream kernel: rows per wave
constexpr int WPW   = 256;   // legacy stream kernel: cols per wave

__global__ __launch_bounds__(256)
void prep_kernel(const float* __restrict__ lat, const float* __restrict__ lon,
                 float* __restrict__ coef, int H) {
    int h = blockIdx.x * blockDim.x + threadIdx.x;
    if (h < H) {
        float dlon = lon[1] - lon[0];
        coef[h] = 1.0f / (R_EARTH * DEG2RAD * dlon * cosf(lat[h] * DEG2RAD));
    }
    if (h == 0) {
        float dlat = lat[1] - lat[0];
        coef[H] = 1.0f / (R_EARTH * DEG2RAD * dlat);
    }
}

// ------------------------- fused 2-step kernel -----------------------------
constexpr int FWAVES = 4;    // waves per block, FWAVES*256 must == W
constexpr int SH2    = 8;    // output rows per block chunk (h0 % 8 == 0!)
constexpr int NITER2 = SH2 + 6;   // 14

__global__ __launch_bounds__(256, 4)
void fused2_kernel(const float* __restrict__ Tin, const float* __restrict__ ug,
                   const float* __restrict__ vg, const float* __restrict__ mask,
                   const float* __restrict__ coef, float* __restrict__ Tout,
                   int H, int W) {
    const int lane = threadIdx.x & 63;
    const int wv   = threadIdx.x >> 6;
    const int h0   = blockIdx.x * SH2;
    const int b    = blockIdx.y;
    const int gw   = (wv << 8) + (lane << 2);
    const size_t plane = (size_t)H * W;
    const float* __restrict__ Tb  = Tin + b * plane;
    const float* __restrict__ ugb = ug  + b * plane;
    const float* __restrict__ vgb = vg  + b * plane;
    float* __restrict__ To = Tout + b * plane;
    const float inv_dy = coef[H];
    const bool isL = (lane == 0), isR = (lane == 63);
    const bool domL = (wv == 0), domR = (wv == FWAVES - 1);

    // edge rings: [row mod 8][wave][0 = first col, 1 = last col]
    __shared__ float eT [8][FWAVES][2];
    __shared__ float eA1[8][FWAVES][2];
    __shared__ float eS1[8][FWAVES][2];
    __shared__ float eA2[8][FWAVES][2];

    auto rowc = [&](int r) { return min(max(r, 0), H - 1); };
    auto ld4 = [&](const float* __restrict__ p, int r) -> float4 {
        return *(const float4*)(p + (size_t)rowc(r) * W + gw);
    };
    const float4 z4 = make_float4(0.f, 0.f, 0.f, 0.f);

    // ---- warm-up: after the j=0 roll, t0..t3 = rows a-1..a+2 (a = h0-3) ----
    float4 t0 = z4;
    float4 t1 = ld4(Tb, h0 - 4);
    float4 t2 = ld4(Tb, h0 - 3);
    float4 t3 = ld4(Tb, h0 - 2);
    float4 a1p = z4, a1c = z4, a1n = z4;
    float4 s1p = z4, s1c = z4, s1n = z4;
    float4 a2p = z4, a2c = z4, a2n = z4;

    // pre-publish eT for rows h0-3 (ring 5), h0-2 (ring 6)  [h0 % 8 == 0]
    if (isL) { eT[5][wv][0] = t2.x; eT[6][wv][0] = t3.x; }
    if (isR) { eT[5][wv][1] = t2.w; eT[6][wv][1] = t3.w; }
    asm volatile("s_waitcnt lgkmcnt(0)" ::: "memory");
    __builtin_amdgcn_s_barrier();

    #pragma unroll
    for (int j = 0; j < NITER2; ++j) {
        const int a = h0 - 3 + j;               // A1 row
        // ring indices (compile-time under unroll; h0 % 8 == 0)
        const int rgA  = (j + 5) & 7;           // row a
        const int rgA1 = (j + 6) & 7;           // row a+1
        const int rgS  = (j + 4) & 7;           // row a-1
        const int rgQ  = (j + 3) & 7;           // row a-2
        const int rgR  = (j + 2) & 7;           // row a-3
        const int rgRm = (j + 1) & 7;           // row a-4

        // ---- roll T chain, issue all loads for this iteration ----
        t0 = t1; t1 = t2; t2 = t3;
        t3 = ld4(Tb, a + 2);                    // prefetch (used next iter)
        // per-stage reloads (rows a-1..a-3 are L1-hot from earlier iters)
        float4 uA = ld4(ugb, a),     gA = ld4(vgb, a),     mA = ld4(mask, a);
        float4 mS = ld4(mask, a - 1);
        float4 uQ = ld4(ugb, a - 2), gQ = ld4(vgb, a - 2), mQ = ld4(mask, a - 2);
        float4 mO = ld4(mask, a - 3);

        // publish T edges for row a+1 (t2: load completed last iteration)
        if (isL) eT[rgA1][wv][0] = t2.x;
        if (isR) eT[rgA1][wv][1] = t2.w;

        // ---------------- A1: advect T at row a ----------------
        float4 a1_new = z4;
        if (a >= 0 && a < H) {
            const float ix  = coef[a];
            const float sy  = (a == 0 || a == H - 1) ? inv_dy : 0.5f * inv_dy;
            const float sxh = 0.5f * ix;
            float cL = __shfl_up(t1.w, 1);
            float cR = __shfl_down(t1.x, 1);
            float sxx = sxh, sxw = sxh;
            if (isL) { if (domL) { cL = t1.x; sxx = ix; } else cL = eT[rgA][wv - 1][1]; }
            if (isR) { if (domR) { cR = t1.w; sxw = ix; } else cR = eT[rgA][wv + 1][0]; }
            a1_new.x = t1.x + DT_S * (-(uA.x * ((t1.y - cL ) * sxx) + gA.x * ((t2.x - t0.x) * sy)) * mA.x);
            a1_new.y = t1.y + DT_S * (-(uA.y * ((t1.z - t1.x) * sxh) + gA.y * ((t2.y - t0.y) * sy)) * mA.y);
            a1_new.z = t1.z + DT_S * (-(uA.z * ((t1.w - t1.y) * sxh) + gA.z * ((t2.z - t0.z) * sy)) * mA.z);
            a1_new.w = t1.w + DT_S * (-(uA.w * ((cR  - t1.z) * sxw) + gA.w * ((t2.w - t0.w) * sy)) * mA.w);
        }
        if (isL) eA1[rgA][wv][0] = a1_new.x;
        if (isR) eA1[rgA][wv][1] = a1_new.w;
        a1n = a1_new;

        // B1: A1 edges visible; global prefetches stay in flight
        asm volatile("s_waitcnt lgkmcnt(0)" ::: "memory");
        __builtin_amdgcn_s_barrier();

        // ---------------- S1: smooth A1 at row a-1 ----------------
        float4 s1_new = z4;
        if (j >= 2) {
            const int s = a - 1;
            if (s >= 0 && s < H) {
                float4 v;
                v.x = a1p.x + 2.f * a1c.x + a1n.x;
                v.y = a1p.y + 2.f * a1c.y + a1n.y;
                v.z = a1p.z + 2.f * a1c.z + a1n.z;
                v.w = a1p.w + 2.f * a1c.w + a1n.w;
                float vL = __shfl_up(v.w, 1);
                float vR = __shfl_down(v.x, 1);
                if (isL) vL = domL ? 0.f
                    : (eA1[rgQ][wv - 1][1] + 2.f * eA1[rgS][wv - 1][1] + eA1[rgA][wv - 1][1]);
                if (isR) vR = domR ? 0.f
                    : (eA1[rgQ][wv + 1][0] + 2.f * eA1[rgS][wv + 1][0] + eA1[rgA][wv + 1][0]);
                s1_new.x = (vL  + 2.f * v.x + v.y) * 0.0625f * mS.x;
                s1_new.y = (v.x + 2.f * v.y + v.z) * 0.0625f * mS.y;
                s1_new.z = (v.y + 2.f * v.z + v.w) * 0.0625f * mS.z;
                s1_new.w = (v.z + 2.f * v.w + vR ) * 0.0625f * mS.w;
            }
            if (isL) eS1[rgS][wv][0] = s1_new.x;
            if (isR) eS1[rgS][wv][1] = s1_new.w;
        }
        a1p = a1c; a1c = a1n;
        s1n = s1_new;

        // ---------------- A2: advect S1 at row a-2 ----------------
        float4 a2_new = z4;
        if (j >= 4) {
            const int q = a - 2;
            if (q >= 0 && q < H) {
                const float ix  = coef[q];
                const float sxh = 0.5f * ix;
                float cL = __shfl_up(s1c.w, 1);
                float cR = __shfl_down(s1c.x, 1);
                float sxx = sxh, sxw = sxh;
                if (isL) { if (domL) { cL = s1c.x; sxx = ix; } else cL = eS1[rgQ][wv - 1][1]; }
                if (isR) { if (domR) { cR = s1c.w; sxw = ix; } else cR = eS1[rgQ][wv + 1][0]; }
                const float4 yl = (q == 0)     ? s1c : s1p;
                const float4 yh = (q == H - 1) ? s1c : s1n;
                const float sy  = (q == 0 || q == H - 1) ? inv_dy : 0.5f * inv_dy;
                a2_new.x = s1c.x + DT_S * (-(uQ.x * ((s1c.y - cL  ) * sxx) + gQ.x * ((yh.x - yl.x) * sy)) * mQ.x);
                a2_new.y = s1c.y + DT_S * (-(uQ.y * ((s1c.z - s1c.x) * sxh) + gQ.y * ((yh.y - yl.y) * sy)) * mQ.y);
                a2_new.z = s1c.z + DT_S * (-(uQ.z * ((s1c.w - s1c.y) * sxh) + gQ.z * ((yh.z - yl.z) * sy)) * mQ.z);
                a2_new.w = s1c.w + DT_S * (-(uQ.w * ((cR   - s1c.z) * sxw) + gQ.w * ((yh.w - yl.w) * sy)) * mQ.w);
            }
            if (isL) eA2[rgQ][wv][0] = a2_new.x;
            if (isR) eA2[rgQ][wv][1] = a2_new.w;
        }
        s1p = s1c; s1c = s1n;
        a2n = a2_new;

        // B2: A2 edges visible
        asm volatile("s_waitcnt lgkmcnt(0)" ::: "memory");
        __builtin_amdgcn_s_barrier();

        // ---------------- out: smooth A2 at row a-3 ----------------
        if (j >= 6) {
            const int r = a - 3;                 // in [h0, h0+SH2)
            if (r < H) {
                float4 v;
                v.x = a2p.x + 2.f * a2c.x + a2n.x;
                v.y = a2p.y + 2.f * a2c.y + a2n.y;
                v.z = a2p.z + 2.f * a2c.z + a2n.z;
                v.w = a2p.w + 2.f * a2c.w + a2n.w;
                float vL = __shfl_up(v.w, 1);
                float vR = __shfl_down(v.x, 1);
                if (isL) vL = domL ? 0.f
                    : (eA2[rgRm][wv - 1][1] + 2.f * eA2[rgR][wv - 1][1] + eA2[rgQ][wv - 1][1]);
                if (isR) vR = domR ? 0.f
                    : (eA2[rgRm][wv + 1][0] + 2.f * eA2[rgR][wv + 1][0] + eA2[rgQ][wv + 1][0]);
                float4 o;
                o.x = (vL  + 2.f * v.x + v.y) * 0.0625f * mO.x;
                o.y = (v.x + 2.f * v.y + v.z) * 0.0625f * mO.y;
                o.z = (v.y + 2.f * v.z + v.w) * 0.0625f * mO.z;
                o.w = (v.z + 2.f * v.w + vR ) * 0.0625f * mO.w;
                *(float4*)(To + (size_t)r * W + gw) = o;
            }
        }
        a2p = a2c; a2c = a2n;
    }
}

// --------- legacy single-step stream kernel (fallback, W % 256 == 0) -------
__global__ __launch_bounds__(256, 4)
void stream_kernel(const float* __restrict__ Tin, const float* __restrict__ ug,
                   const float* __restrict__ vg, const float* __restrict__ mask,
                   const float* __restrict__ coef, float* __restrict__ Tout,
                   int H, int W) {
    const int lane = threadIdx.x & 63;
    const int wv   = threadIdx.x >> 6;
    const int ws   = blockIdx.x * WPW;
    const int hs   = (blockIdx.y * 4 + wv) * STRIP;
    const int b    = blockIdx.z;
    if (hs >= H) return;
    const size_t plane = (size_t)H * W;
    const float* __restrict__ Tb  = Tin + b * plane;
    const float* __restrict__ ugb = ug  + b * plane;
    const float* __restrict__ vgb = vg  + b * plane;
    float* __restrict__ To = Tout + b * plane;
    const float inv_dy = coef[H];
    const bool atL = (ws == 0);
    const bool atR = (ws + WPW >= W);
    const bool isL = (lane == 0);
    const bool isR = (lane == 63);
    const int gw = ws + 4 * lane;

    auto clampr = [&](int r) { return min(max(r, 0), H - 1); };
    auto ldT = [&](int r) -> float4 {
        return *(const float4*)(Tb + (size_t)clampr(r) * W + gw);
    };
    auto ldL = [&](int r) -> float2 {
        float4 q = *(const float4*)(Tb + (size_t)clampr(r) * W + (ws - 4));
        return make_float2(q.z, q.w);
    };
    auto ldR = [&](int r) -> float2 {
        float4 q = *(const float4*)(Tb + (size_t)clampr(r) * W + (ws + WPW));
        return make_float2(q.x, q.y);
    };

    float4 tp, tc, tn;
    float  tLp_w = 0.f; float2 tLc = make_float2(0.f, 0.f), tLn = make_float2(0.f, 0.f);
    float  tRp_x = 0.f; float2 tRc = make_float2(0.f, 0.f), tRn = make_float2(0.f, 0.f);

    auto roll = [&](int rnext) {
        tp = tc; tc = tn; tn = ldT(rnext);
        if (!atL) { tLp_w = tLc.y; tLc = tLn; tLn = ldL(rnext); }
        if (!atR) { tRp_x = tRc.x; tRc = tRn; tRn = ldR(rnext); }
    };

    auto advrow = [&](int r, float4& a, float& aL, float& aR, float4& mOut) {
        if (r < 0 || r >= H) {
            a = make_float4(0.f, 0.f, 0.f, 0.f); aL = 0.f; aR = 0.f;
            mOut = make_float4(0.f, 0.f, 0.f, 0.f); return;
        }
        const size_t ro = (size_t)r * W;
        const float ix  = coef[r];
        const float sy  = (r == 0 || r == H - 1) ? inv_dy : 0.5f * inv_dy;
        const float sxh = 0.5f * ix;
        float4 u4 = *(const float4*)(ugb + ro + gw);
        float4 g4 = *(const float4*)(vgb + ro + gw);
        float4 m4 = *(const float4*)(mask + ro + gw);
        float cLw = __shfl_up(tc.w, 1);
        float cRx = __shfl_down(tc.x, 1);
        float sxx = sxh, sxw = sxh;
        if (isL) { if (atL) { cLw = tc.x; sxx = ix; } else { cLw = tLc.y; } }
        if (isR) { if (atR) { cRx = tc.w; sxw = ix; } else { cRx = tRc.x; } }
        a.x = tc.x + DT_S * (-(u4.x * ((tc.y - cLw) * sxx) + g4.x * ((tn.x - tp.x) * sy)) * m4.x);
        a.y = tc.y + DT_S * (-(u4.y * ((tc.z - tc.x) * sxh) + g4.y * ((tn.y - tp.y) * sy)) * m4.y);
        a.z = tc.z + DT_S * (-(u4.z * ((tc.w - tc.y) * sxh) + g4.z * ((tn.z - tp.z) * sy)) * m4.z);
        a.w = tc.w + DT_S * (-(u4.w * ((cRx - tc.z) * sxw) + g4.w * ((tn.w - tp.w) * sy)) * m4.w);
        if (!atL) {
            float uL = ((const float4*)(ugb + ro + (ws - 4)))->w;
            float gL = ((const float4*)(vgb + ro + (ws - 4)))->w;
            float mL = ((const float4*)(mask + ro + (ws - 4)))->w;
            aL = tLc.y + DT_S * (-(uL * ((tc.x - tLc.x) * sxh) + gL * ((tLn.y - tLp_w) * sy)) * mL);
        } else aL = 0.f;
        if (!atR) {
            float uR = ((const float4*)(ugb + ro + (ws + WPW)))->x;
            float gR = ((const float4*)(vgb + ro + (ws + WPW)))->x;
            float mR = ((const float4*)(mask + ro + (ws + WPW)))->x;
            aR = tRc.x + DT_S * (-(uR * ((tRc.y - tc.w) * sxh) + gR * ((tRn.x - tRp_x) * sy)) * mR);
        } else aR = 0.f;
        mOut = m4;
    };

    tp = ldT(hs - 2); tc = ldT(hs - 1); tn = ldT(hs);
    if (!atL) { float2 q = ldL(hs - 2); tLp_w = q.y; tLc = ldL(hs - 1); tLn = ldL(hs); }
    if (!atR) { float2 q = ldR(hs - 2); tRp_x = q.x; tRc = ldR(hs - 1); tRn = ldR(hs); }

    float4 ap, ac, an, mC, mN, mdum;
    float aLp, aLc, aLn, aRp, aRc, aRn;
    advrow(hs - 1, ap, aLp, aRp, mdum);
    roll(hs + 1);
    advrow(hs, ac, aLc, aRc, mC);

    #pragma unroll
    for (int i = 0; i < STRIP; ++i) {
        const int go = hs + i;
        roll(go + 2);
        advrow(go + 1, an, aLn, aRn, mN);
        if (go < H) {
            float4 v;
            v.x = ap.x + 2.f * ac.x + an.x;
            v.y = ap.y + 2.f * ac.y + an.y;
            v.z = ap.z + 2.f * ac.z + an.z;
            v.w = ap.w + 2.f * ac.w + an.w;
            float vL  = aLp + 2.f * aLc + aLn;
            float vR  = aRp + 2.f * aRc + aRn;
            float vLw = __shfl_up(v.w, 1);
            float vRx = __shfl_down(v.x, 1);
            if (isL) vLw = atL ? 0.f : vL;
            if (isR) vRx = atR ? 0.f : vR;
            float4 o;
            o.x = (vLw + 2.f * v.x + v.y) * 0.0625f * mC.x;
            o.y = (v.x + 2.f * v.y + v.z) * 0.0625f * mC.y;
            o.z = (v.y + 2.f * v.z + v.w) * 0.0625f * mC.z;
            o.w = (v.z + 2.f * v.w + vRx) * 0.0625f * mC.w;
            *(float4*)(To + (size_t)go * W + gw) = o;
        }
        ap = ac; ac = an;
        aLp = aLc; aLc = aLn; aRp = aRc; aRc = aRn;
        mC = mN;
    }
}

// ---------- generic fallback (round-1 LDS tile kernel, validated) ----------
constexpr int FTW = 64, FTH = 32;
constexpr int FSTW = FTW + 4, FSTH = FTH + 4;
constexpr int FMTW = FTW + 2, FMTH = FTH + 2;

__global__ __launch_bounds__(256)
void step_tile(const float* __restrict__ Tin, const float* __restrict__ ug,
               const float* __restrict__ vg, const float* __restrict__ mask,
               const float* __restrict__ coef, float* __restrict__ Tout,
               int H, int W) {
    __shared__ float sT[FSTH][FSTW];
    __shared__ float sM[FMTH][FMTW];
    const int tid = threadIdx.x;
    const int w0 = blockIdx.x * FTW;
    const int h0 = blockIdx.y * FTH;
    const int b  = blockIdx.z;
    const long plane = (long)H * W;
    const float* Tb  = Tin + b * plane;
    const float* ugb = ug  + b * plane;
    const float* vgb = vg  + b * plane;
    const float inv_dy = coef[H];

    for (int i = tid; i < FSTH * FSTW; i += NT) {
        int r = i / FSTW, c = i - r * FSTW;
        int gh = min(max(h0 - 2 + r, 0), H - 1);
        int gw = min(max(w0 - 2 + c, 0), W - 1);
        sT[r][c] = Tb[gh * W + gw];
    }
    __syncthreads();
    for (int i = tid; i < FMTH * FMTW; i += NT) {
        int r = i / FMTW, c = i - r * FMTW;
        int gh = h0 - 1 + r, gw = w0 - 1 + c;
        float v = 0.0f;
        if (gh >= 0 && gh < H && gw >= 0 && gw < W) {
            int sr = r + 1, sc = c + 1;
            float ndy = sT[sr + 1][sc] - sT[sr - 1][sc];
            float ndx = sT[sr][sc + 1] - sT[sr][sc - 1];
            float sy  = (gh == 0 || gh == H - 1) ? inv_dy : 0.5f * inv_dy;
            float ix  = coef[gh];
            float sx  = (gw == 0 || gw == W - 1) ? ix : 0.5f * ix;
            int   gi  = gh * W + gw;
            float F   = -(ugb[gi] * (ndx * sx) + vgb[gi] * (ndy * sy)) * mask[gi];
            v = sT[sr][sc] + DT_S * F;
        }
        sM[r][c] = v;
    }
    __syncthreads();
    float* To = Tout + b * plane;
    for (int i = tid; i < FTH * FTW; i += NT) {
        int r = i >> 6, c = i & (FTW - 1);
        int gh = h0 + r, gw = w0 + c;
        if (gh < H && gw < W) {
            int sr = r + 1, sc = c + 1;
            float s = (sM[sr-1][sc-1] + sM[sr-1][sc+1] + sM[sr+1][sc-1] + sM[sr+1][sc+1])
                    + 2.0f * (sM[sr-1][sc] + sM[sr+1][sc] + sM[sr][sc-1] + sM[sr][sc+1])
                    + 4.0f * sM[sr][sc];
            To[gh * W + gw] = s * 0.0625f * mask[gh * W + gw];
        }
    }
}

extern "C" void kernel_launch(void* const* d_in, const int* in_sizes, int n_in,
                              void* d_out, int out_size, void* d_ws, size_t ws_size,
                              hipStream_t stream) {
    const float* T0   = (const float*)d_in[0];
    const float* ug   = (const float*)d_in[1];
    const float* vg   = (const float*)d_in[2];
    const float* lat  = (const float*)d_in[3];
    const float* lon  = (const float*)d_in[4];
    const float* mask = (const float*)d_in[5];

    const int H = in_sizes[3];
    const int W = in_sizes[4];
    const int B = in_sizes[0] / (H * W);

    float* out  = (float*)d_out;
    float* ping = (float*)d_ws;                 // B*H*W floats
    float* coef = ping + (size_t)B * H * W;     // H+1 floats: 1/dx[h], then 1/dy

    prep_kernel<<<dim3((H + NT - 1) / NT), dim3(NT), 0, stream>>>(lat, lon, coef, H);

    const int STEPS = 48;

    if (W == FWAVES * 256) {
        // fused 2-step path: 24 launches, each = 2 simulated steps
        dim3 gridF2((H + SH2 - 1) / SH2, B);    // 128 x 8 = 1024 blocks
        const int NLAUNCH = STEPS / 2;          // 24, even -> last dst == out
        for (int i = 0; i < NLAUNCH; ++i) {
            const float* src = (i == 0) ? T0 : ((i & 1) ? ping : out);
            float*       dst = (i & 1) ? out : ping;
            fused2_kernel<<<gridF2, dim3(NT), 0, stream>>>(src, ug, vg, mask, coef, dst, H, W);
        }
    } else {
        const bool fast = (W % WPW) == 0;
        dim3 gridS(W / (fast ? WPW : 1), (H + 4 * STRIP - 1) / (4 * STRIP), B);
        dim3 gridF((W + FTW - 1) / FTW, (H + FTH - 1) / FTH, B);
        for (int i = 0; i < STEPS; ++i) {
            const float* src = (i == 0) ? T0 : ((i & 1) ? ping : out);
            float*       dst = (i & 1) ? out : ping;
            if (fast)
                stream_kernel<<<gridS, dim3(NT), 0, stream>>>(src, ug, vg, mask, coef, dst, H, W);
            else
                step_tile<<<gridF, dim3(NT), 0, stream>>>(src, ug, vg, mask, coef, dst, H, W);
        }
    }
}

// Round 11
// 1137.799 us; speedup vs baseline: 1.7718x; 1.2688x over previous
//
#include <hip/hip_runtime.h>

// Ocean advection + 3x3 binomial smoothing, 48 steps, fp32.
//
// ROUND-11: K=2 fusion at 4 blocks/CU, SPILL FIXED BY LOAD PLACEMENT.
// Round-10 spilled (WRITE 51MB, T_iter 4.3us) because ALL per-iter loads were
// hoisted to the iteration top: the barrier asm's "memory" clobber prevents
// sinking them, so uQ/gQ/mQ (used post-B1) and mO (post-B2) stayed live
// across both barriers -> peak ~84 regs > 64 cap. Fix: issue each stage's
// loads INSIDE its phase (after the barrier, next to the consumer). The
// clobber now guarantees short live ranges: cross-barrier live set ~40 regs
// (t1-t3 + rolled chains), peak ~60 -> fits cap 64, no spill. The reloaded
// rows are L1-hot (loaded as "row a" 1-3 iters earlier by this block).
// Residency model (validated: round-5 = 16 x 26 x 2.1us = 872us exactly):
// wall = NITER x T_iter when grid fully resident. K=2/SH=8/bpc=4 is the only
// cell that beats the champion: 24 x 14 x ~2us ~= 650-790us.
// Tripwires: VGPR<=64; WRITE_SIZE 32768 KB (<=35MB tolerated); occ 40-48%.
// If spilled again -> revert to K=3/SH=16/(256,2) 872us champion.

#define DEG2RAD 0.017453292519943295f
#define R_EARTH 6371000.0f
#define DT_S 600.0f

constexpr int NT    = 256;   // threads per block
constexpr int STRIP = 8;     // legacy stream kernel: rows per wave
constexpr int WPW   = 256;   // legacy stream kernel: cols per wave

__global__ __launch_bounds__(256)
void prep_kernel(const float* __restrict__ lat, const float* __restrict__ lon,
                 float* __restrict__ coef, int H) {
    int h = blockIdx.x * blockDim.x + threadIdx.x;
    if (h < H) {
        float dlon = lon[1] - lon[0];
        coef[h] = 1.0f / (R_EARTH * DEG2RAD * dlon * cosf(lat[h] * DEG2RAD));
    }
    if (h == 0) {
        float dlat = lat[1] - lat[0];
        coef[H] = 1.0f / (R_EARTH * DEG2RAD * dlat);
    }
}

// ------------------------- fused 2-step kernel -----------------------------
constexpr int FWAVES = 4;    // waves per block, FWAVES*256 must == W
constexpr int SH2    = 8;    // output rows per block chunk (h0 % 8 == 0!)
constexpr int NITER2 = SH2 + 6;   // 14

__global__ __launch_bounds__(256, 4)
void fused2_kernel(const float* __restrict__ Tin, const float* __restrict__ ug,
                   const float* __restrict__ vg, const float* __restrict__ mask,
                   const float* __restrict__ coef, float* __restrict__ Tout,
                   int H, int W) {
    const int lane = threadIdx.x & 63;
    const int wv   = threadIdx.x >> 6;
    const int h0   = blockIdx.x * SH2;
    const int b    = blockIdx.y;
    const int gw   = (wv << 8) + (lane << 2);
    const size_t plane = (size_t)H * W;
    const float* __restrict__ Tb  = Tin + b * plane;
    const float* __restrict__ ugb = ug  + b * plane;
    const float* __restrict__ vgb = vg  + b * plane;
    float* __restrict__ To = Tout + b * plane;
    const float inv_dy = coef[H];
    const bool isL = (lane == 0), isR = (lane == 63);
    const bool domL = (wv == 0), domR = (wv == FWAVES - 1);

    // edge rings: [row mod 8][wave][0 = first col, 1 = last col]
    __shared__ float eT [8][FWAVES][2];
    __shared__ float eA1[8][FWAVES][2];
    __shared__ float eS1[8][FWAVES][2];
    __shared__ float eA2[8][FWAVES][2];

    auto rowc = [&](int r) { return min(max(r, 0), H - 1); };
    auto ld4 = [&](const float* __restrict__ p, int r) -> float4 {
        return *(const float4*)(p + (size_t)rowc(r) * W + gw);
    };
    const float4 z4 = make_float4(0.f, 0.f, 0.f, 0.f);

    // ---- warm-up: after the j=0 roll, t0..t3 = rows a-1..a+2 (a = h0-3) ----
    float4 t0 = z4;
    float4 t1 = ld4(Tb, h0 - 4);
    float4 t2 = ld4(Tb, h0 - 3);
    float4 t3 = ld4(Tb, h0 - 2);
    float4 a1p = z4, a1c = z4, a1n = z4;
    float4 s1p = z4, s1c = z4, s1n = z4;
    float4 a2p = z4, a2c = z4, a2n = z4;

    // pre-publish eT for rows h0-3 (ring 5), h0-2 (ring 6)  [h0 % 8 == 0]
    if (isL) { eT[5][wv][0] = t2.x; eT[6][wv][0] = t3.x; }
    if (isR) { eT[5][wv][1] = t2.w; eT[6][wv][1] = t3.w; }
    asm volatile("s_waitcnt lgkmcnt(0)" ::: "memory");
    __builtin_amdgcn_s_barrier();

    #pragma unroll
    for (int j = 0; j < NITER2; ++j) {
        const int a = h0 - 3 + j;               // A1 row
        // ring indices (compile-time under unroll; h0 % 8 == 0)
        const int rgA  = (j + 5) & 7;           // row a
        const int rgA1 = (j + 6) & 7;           // row a+1
        const int rgS  = (j + 4) & 7;           // row a-1
        const int rgQ  = (j + 3) & 7;           // row a-2
        const int rgR  = (j + 2) & 7;           // row a-3
        const int rgRm = (j + 1) & 7;           // row a-4

        // ---- roll T chain; issue ONLY this phase's loads (A1 inputs) ----
        t0 = t1; t1 = t2; t2 = t3;
        t3 = ld4(Tb, a + 2);                    // prefetch (used next iter)
        float4 uA = ld4(ugb, a), gA = ld4(vgb, a), mA = ld4(mask, a);

        // publish T edges for row a+1 (t2: load completed last iteration)
        if (isL) eT[rgA1][wv][0] = t2.x;
        if (isR) eT[rgA1][wv][1] = t2.w;

        // ---------------- A1: advect T at row a ----------------
        float4 a1_new = z4;
        if (a >= 0 && a < H) {
            const float ix  = coef[a];
            const float sy  = (a == 0 || a == H - 1) ? inv_dy : 0.5f * inv_dy;
            const float sxh = 0.5f * ix;
            float cL = __shfl_up(t1.w, 1);
            float cR = __shfl_down(t1.x, 1);
            float sxx = sxh, sxw = sxh;
            if (isL) { if (domL) { cL = t1.x; sxx = ix; } else cL = eT[rgA][wv - 1][1]; }
            if (isR) { if (domR) { cR = t1.w; sxw = ix; } else cR = eT[rgA][wv + 1][0]; }
            a1_new.x = t1.x + DT_S * (-(uA.x * ((t1.y - cL ) * sxx) + gA.x * ((t2.x - t0.x) * sy)) * mA.x);
            a1_new.y = t1.y + DT_S * (-(uA.y * ((t1.z - t1.x) * sxh) + gA.y * ((t2.y - t0.y) * sy)) * mA.y);
            a1_new.z = t1.z + DT_S * (-(uA.z * ((t1.w - t1.y) * sxh) + gA.z * ((t2.z - t0.z) * sy)) * mA.z);
            a1_new.w = t1.w + DT_S * (-(uA.w * ((cR  - t1.z) * sxw) + gA.w * ((t2.w - t0.w) * sy)) * mA.w);
        }
        if (isL) eA1[rgA][wv][0] = a1_new.x;
        if (isR) eA1[rgA][wv][1] = a1_new.w;
        a1n = a1_new;

        // B1: A1 edges visible; global prefetches stay in flight
        asm volatile("s_waitcnt lgkmcnt(0)" ::: "memory");
        __builtin_amdgcn_s_barrier();

        // ---------------- S1: smooth A1 at row a-1 ----------------
        // (mS loaded HERE, post-B1: short live range, L1-hot row a-1)
        float4 s1_new = z4;
        if (j >= 2) {
            const int s = a - 1;
            if (s >= 0 && s < H) {
                float4 mS = ld4(mask, s);
                float4 v;
                v.x = a1p.x + 2.f * a1c.x + a1n.x;
                v.y = a1p.y + 2.f * a1c.y + a1n.y;
                v.z = a1p.z + 2.f * a1c.z + a1n.z;
                v.w = a1p.w + 2.f * a1c.w + a1n.w;
                float vL = __shfl_up(v.w, 1);
                float vR = __shfl_down(v.x, 1);
                if (isL) vL = domL ? 0.f
                    : (eA1[rgQ][wv - 1][1] + 2.f * eA1[rgS][wv - 1][1] + eA1[rgA][wv - 1][1]);
                if (isR) vR = domR ? 0.f
                    : (eA1[rgQ][wv + 1][0] + 2.f * eA1[rgS][wv + 1][0] + eA1[rgA][wv + 1][0]);
                s1_new.x = (vL  + 2.f * v.x + v.y) * 0.0625f * mS.x;
                s1_new.y = (v.x + 2.f * v.y + v.z) * 0.0625f * mS.y;
                s1_new.z = (v.y + 2.f * v.z + v.w) * 0.0625f * mS.z;
                s1_new.w = (v.z + 2.f * v.w + vR ) * 0.0625f * mS.w;
            }
            if (isL) eS1[rgS][wv][0] = s1_new.x;
            if (isR) eS1[rgS][wv][1] = s1_new.w;
        }
        a1p = a1c; a1c = a1n;
        s1n = s1_new;

        // ---------------- A2: advect S1 at row a-2 ----------------
        // (uQ/gQ/mQ loaded HERE, post-B1: short live range, L1-hot row a-2)
        float4 a2_new = z4;
        if (j >= 4) {
            const int q = a - 2;
            if (q >= 0 && q < H) {
                float4 uQ = ld4(ugb, q), gQ = ld4(vgb, q), mQ = ld4(mask, q);
                const float ix  = coef[q];
                const float sxh = 0.5f * ix;
                float cL = __shfl_up(s1c.w, 1);
                float cR = __shfl_down(s1c.x, 1);
                float sxx = sxh, sxw = sxh;
                if (isL) { if (domL) { cL = s1c.x; sxx = ix; } else cL = eS1[rgQ][wv - 1][1]; }
                if (isR) { if (domR) { cR = s1c.w; sxw = ix; } else cR = eS1[rgQ][wv + 1][0]; }
                const float4 yl = (q == 0)     ? s1c : s1p;
                const float4 yh = (q == H - 1) ? s1c : s1n;
                const float sy  = (q == 0 || q == H - 1) ? inv_dy : 0.5f * inv_dy;
                a2_new.x = s1c.x + DT_S * (-(uQ.x * ((s1c.y - cL  ) * sxx) + gQ.x * ((yh.x - yl.x) * sy)) * mQ.x);
                a2_new.y = s1c.y + DT_S * (-(uQ.y * ((s1c.z - s1c.x) * sxh) + gQ.y * ((yh.y - yl.y) * sy)) * mQ.y);
                a2_new.z = s1c.z + DT_S * (-(uQ.z * ((s1c.w - s1c.y) * sxh) + gQ.z * ((yh.z - yl.z) * sy)) * mQ.z);
                a2_new.w = s1c.w + DT_S * (-(uQ.w * ((cR   - s1c.z) * sxw) + gQ.w * ((yh.w - yl.w) * sy)) * mQ.w);
            }
            if (isL) eA2[rgQ][wv][0] = a2_new.x;
            if (isR) eA2[rgQ][wv][1] = a2_new.w;
        }
        s1p = s1c; s1c = s1n;
        a2n = a2_new;

        // B2: A2 edges visible
        asm volatile("s_waitcnt lgkmcnt(0)" ::: "memory");
        __builtin_amdgcn_s_barrier();

        // ---------------- out: smooth A2 at row a-3 ----------------
        // (mO loaded HERE, post-B2: short live range, L1-hot row a-3)
        if (j >= 6) {
            const int r = a - 3;                 // in [h0, h0+SH2)
            if (r < H) {
                float4 mO = ld4(mask, r);
                float4 v;
                v.x = a2p.x + 2.f * a2c.x + a2n.x;
                v.y = a2p.y + 2.f * a2c.y + a2n.y;
                v.z = a2p.z + 2.f * a2c.z + a2n.z;
                v.w = a2p.w + 2.f * a2c.w + a2n.w;
                float vL = __shfl_up(v.w, 1);
                float vR = __shfl_down(v.x, 1);
                if (isL) vL = domL ? 0.f
                    : (eA2[rgRm][wv - 1][1] + 2.f * eA2[rgR][wv - 1][1] + eA2[rgQ][wv - 1][1]);
                if (isR) vR = domR ? 0.f
                    : (eA2[rgRm][wv + 1][0] + 2.f * eA2[rgR][wv + 1][0] + eA2[rgQ][wv + 1][0]);
                float4 o;
                o.x = (vL  + 2.f * v.x + v.y) * 0.0625f * mO.x;
                o.y = (v.x + 2.f * v.y + v.z) * 0.0625f * mO.y;
                o.z = (v.y + 2.f * v.z + v.w) * 0.0625f * mO.z;
                o.w = (v.z + 2.f * v.w + vR ) * 0.0625f * mO.w;
                *(float4*)(To + (size_t)r * W + gw) = o;
            }
        }
        a2p = a2c; a2c = a2n;
    }
}

// --------- legacy single-step stream kernel (fallback, W % 256 == 0) -------
__global__ __launch_bounds__(256, 4)
void stream_kernel(const float* __restrict__ Tin, const float* __restrict__ ug,
                   const float* __restrict__ vg, const float* __restrict__ mask,
                   const float* __restrict__ coef, float* __restrict__ Tout,
                   int H, int W) {
    const int lane = threadIdx.x & 63;
    const int wv   = threadIdx.x >> 6;
    const int ws   = blockIdx.x * WPW;
    const int hs   = (blockIdx.y * 4 + wv) * STRIP;
    const int b    = blockIdx.z;
    if (hs >= H) return;
    const size_t plane = (size_t)H * W;
    const float* __restrict__ Tb  = Tin + b * plane;
    const float* __restrict__ ugb = ug  + b * plane;
    const float* __restrict__ vgb = vg  + b * plane;
    float* __restrict__ To = Tout + b * plane;
    const float inv_dy = coef[H];
    const bool atL = (ws == 0);
    const bool atR = (ws + WPW >= W);
    const bool isL = (lane == 0);
    const bool isR = (lane == 63);
    const int gw = ws + 4 * lane;

    auto clampr = [&](int r) { return min(max(r, 0), H - 1); };
    auto ldT = [&](int r) -> float4 {
        return *(const float4*)(Tb + (size_t)clampr(r) * W + gw);
    };
    auto ldL = [&](int r) -> float2 {
        float4 q = *(const float4*)(Tb + (size_t)clampr(r) * W + (ws - 4));
        return make_float2(q.z, q.w);
    };
    auto ldR = [&](int r) -> float2 {
        float4 q = *(const float4*)(Tb + (size_t)clampr(r) * W + (ws + WPW));
        return make_float2(q.x, q.y);
    };

    float4 tp, tc, tn;
    float  tLp_w = 0.f; float2 tLc = make_float2(0.f, 0.f), tLn = make_float2(0.f, 0.f);
    float  tRp_x = 0.f; float2 tRc = make_float2(0.f, 0.f), tRn = make_float2(0.f, 0.f);

    auto roll = [&](int rnext) {
        tp = tc; tc = tn; tn = ldT(rnext);
        if (!atL) { tLp_w = tLc.y; tLc = tLn; tLn = ldL(rnext); }
        if (!atR) { tRp_x = tRc.x; tRc = tRn; tRn = ldR(rnext); }
    };

    auto advrow = [&](int r, float4& a, float& aL, float& aR, float4& mOut) {
        if (r < 0 || r >= H) {
            a = make_float4(0.f, 0.f, 0.f, 0.f); aL = 0.f; aR = 0.f;
            mOut = make_float4(0.f, 0.f, 0.f, 0.f); return;
        }
        const size_t ro = (size_t)r * W;
        const float ix  = coef[r];
        const float sy  = (r == 0 || r == H - 1) ? inv_dy : 0.5f * inv_dy;
        const float sxh = 0.5f * ix;
        float4 u4 = *(const float4*)(ugb + ro + gw);
        float4 g4 = *(const float4*)(vgb + ro + gw);
        float4 m4 = *(const float4*)(mask + ro + gw);
        float cLw = __shfl_up(tc.w, 1);
        float cRx = __shfl_down(tc.x, 1);
        float sxx = sxh, sxw = sxh;
        if (isL) { if (atL) { cLw = tc.x; sxx = ix; } else { cLw = tLc.y; } }
        if (isR) { if (atR) { cRx = tc.w; sxw = ix; } else { cRx = tRc.x; } }
        a.x = tc.x + DT_S * (-(u4.x * ((tc.y - cLw) * sxx) + g4.x * ((tn.x - tp.x) * sy)) * m4.x);
        a.y = tc.y + DT_S * (-(u4.y * ((tc.z - tc.x) * sxh) + g4.y * ((tn.y - tp.y) * sy)) * m4.y);
        a.z = tc.z + DT_S * (-(u4.z * ((tc.w - tc.y) * sxh) + g4.z * ((tn.z - tp.z) * sy)) * m4.z);
        a.w = tc.w + DT_S * (-(u4.w * ((cRx - tc.z) * sxw) + g4.w * ((tn.w - tp.w) * sy)) * m4.w);
        if (!atL) {
            float uL = ((const float4*)(ugb + ro + (ws - 4)))->w;
            float gL = ((const float4*)(vgb + ro + (ws - 4)))->w;
            float mL = ((const float4*)(mask + ro + (ws - 4)))->w;
            aL = tLc.y + DT_S * (-(uL * ((tc.x - tLc.x) * sxh) + gL * ((tLn.y - tLp_w) * sy)) * mL);
        } else aL = 0.f;
        if (!atR) {
            float uR = ((const float4*)(ugb + ro + (ws + WPW)))->x;
            float gR = ((const float4*)(vgb + ro + (ws + WPW)))->x;
            float mR = ((const float4*)(mask + ro + (ws + WPW)))->x;
            aR = tRc.x + DT_S * (-(uR * ((tRc.y - tc.w) * sxh) + gR * ((tRn.x - tRp_x) * sy)) * mR);
        } else aR = 0.f;
        mOut = m4;
    };

    tp = ldT(hs - 2); tc = ldT(hs - 1); tn = ldT(hs);
    if (!atL) { float2 q = ldL(hs - 2); tLp_w = q.y; tLc = ldL(hs - 1); tLn = ldL(hs); }
    if (!atR) { float2 q = ldR(hs - 2); tRp_x = q.x; tRc = ldR(hs - 1); tRn = ldR(hs); }

    float4 ap, ac, an, mC, mN, mdum;
    float aLp, aLc, aLn, aRp, aRc, aRn;
    advrow(hs - 1, ap, aLp, aRp, mdum);
    roll(hs + 1);
    advrow(hs, ac, aLc, aRc, mC);

    #pragma unroll
    for (int i = 0; i < STRIP; ++i) {
        const int go = hs + i;
        roll(go + 2);
        advrow(go + 1, an, aLn, aRn, mN);
        if (go < H) {
            float4 v;
            v.x = ap.x + 2.f * ac.x + an.x;
            v.y = ap.y + 2.f * ac.y + an.y;
            v.z = ap.z + 2.f * ac.z + an.z;
            v.w = ap.w + 2.f * ac.w + an.w;
            float vL  = aLp + 2.f * aLc + aLn;
            float vR  = aRp + 2.f * aRc + aRn;
            float vLw = __shfl_up(v.w, 1);
            float vRx = __shfl_down(v.x, 1);
            if (isL) vLw = atL ? 0.f : vL;
            if (isR) vRx = atR ? 0.f : vR;
            float4 o;
            o.x = (vLw + 2.f * v.x + v.y) * 0.0625f * mC.x;
            o.y = (v.x + 2.f * v.y + v.z) * 0.0625f * mC.y;
            o.z = (v.y + 2.f * v.z + v.w) * 0.0625f * mC.z;
            o.w = (v.z + 2.f * v.w + vRx) * 0.0625f * mC.w;
            *(float4*)(To + (size_t)go * W + gw) = o;
        }
        ap = ac; ac = an;
        aLp = aLc; aLc = aLn; aRp = aRc; aRc = aRn;
        mC = mN;
    }
}

// ---------- generic fallback (round-1 LDS tile kernel, validated) ----------
constexpr int FTW = 64, FTH = 32;
constexpr int FSTW = FTW + 4, FSTH = FTH + 4;
constexpr int FMTW = FTW + 2, FMTH = FTH + 2;

__global__ __launch_bounds__(256)
void step_tile(const float* __restrict__ Tin, const float* __restrict__ ug,
               const float* __restrict__ vg, const float* __restrict__ mask,
               const float* __restrict__ coef, float* __restrict__ Tout,
               int H, int W) {
    __shared__ float sT[FSTH][FSTW];
    __shared__ float sM[FMTH][FMTW];
    const int tid = threadIdx.x;
    const int w0 = blockIdx.x * FTW;
    const int h0 = blockIdx.y * FTH;
    const int b  = blockIdx.z;
    const long plane = (long)H * W;
    const float* Tb  = Tin + b * plane;
    const float* ugb = ug  + b * plane;
    const float* vgb = vg  + b * plane;
    const float inv_dy = coef[H];

    for (int i = tid; i < FSTH * FSTW; i += NT) {
        int r = i / FSTW, c = i - r * FSTW;
        int gh = min(max(h0 - 2 + r, 0), H - 1);
        int gw = min(max(w0 - 2 + c, 0), W - 1);
        sT[r][c] = Tb[gh * W + gw];
    }
    __syncthreads();
    for (int i = tid; i < FMTH * FMTW; i += NT) {
        int r = i / FMTW, c = i - r * FMTW;
        int gh = h0 - 1 + r, gw = w0 - 1 + c;
        float v = 0.0f;
        if (gh >= 0 && gh < H && gw >= 0 && gw < W) {
            int sr = r + 1, sc = c + 1;
            float ndy = sT[sr + 1][sc] - sT[sr - 1][sc];
            float ndx = sT[sr][sc + 1] - sT[sr][sc - 1];
            float sy  = (gh == 0 || gh == H - 1) ? inv_dy : 0.5f * inv_dy;
            float ix  = coef[gh];
            float sx  = (gw == 0 || gw == W - 1) ? ix : 0.5f * ix;
            int   gi  = gh * W + gw;
            float F   = -(ugb[gi] * (ndx * sx) + vgb[gi] * (ndy * sy)) * mask[gi];
            v = sT[sr][sc] + DT_S * F;
        }
        sM[r][c] = v;
    }
    __syncthreads();
    float* To = Tout + b * plane;
    for (int i = tid; i < FTH * FTW; i += NT) {
        int r = i >> 6, c = i & (FTW - 1);
        int gh = h0 + r, gw = w0 + c;
        if (gh < H && gw < W) {
            int sr = r + 1, sc = c + 1;
            float s = (sM[sr-1][sc-1] + sM[sr-1][sc+1] + sM[sr+1][sc-1] + sM[sr+1][sc+1])
                    + 2.0f * (sM[sr-1][sc] + sM[sr+1][sc] + sM[sr][sc-1] + sM[sr][sc+1])
                    + 4.0f * sM[sr][sc];
            To[gh * W + gw] = s * 0.0625f * mask[gh * W + gw];
        }
    }
}

extern "C" void kernel_launch(void* const* d_in, const int* in_sizes, int n_in,
                              void* d_out, int out_size, void* d_ws, size_t ws_size,
                              hipStream_t stream) {
    const float* T0   = (const float*)d_in[0];
    const float* ug   = (const float*)d_in[1];
    const float* vg   = (const float*)d_in[2];
    const float* lat  = (const float*)d_in[3];
    const float* lon  = (const float*)d_in[4];
    const float* mask = (const float*)d_in[5];

    const int H = in_sizes[3];
    const int W = in_sizes[4];
    const int B = in_sizes[0] / (H * W);

    float* out  = (float*)d_out;
    float* ping = (float*)d_ws;                 // B*H*W floats
    float* coef = ping + (size_t)B * H * W;     // H+1 floats: 1/dx[h], then 1/dy

    prep_kernel<<<dim3((H + NT - 1) / NT), dim3(NT), 0, stream>>>(lat, lon, coef, H);

    const int STEPS = 48;

    if (W == FWAVES * 256) {
        // fused 2-step path: 24 launches, each = 2 simulated steps
        dim3 gridF2((H + SH2 - 1) / SH2, B);    // 128 x 8 = 1024 blocks
        const int NLAUNCH = STEPS / 2;          // 24, even -> last dst == out
        for (int i = 0; i < NLAUNCH; ++i) {
            const float* src = (i == 0) ? T0 : ((i & 1) ? ping : out);
            float*       dst = (i & 1) ? out : ping;
            fused2_kernel<<<gridF2, dim3(NT), 0, stream>>>(src, ug, vg, mask, coef, dst, H, W);
        }
    } else {
        const bool fast = (W % WPW) == 0;
        dim3 gridS(W / (fast ? WPW : 1), (H + 4 * STRIP - 1) / (4 * STRIP), B);
        dim3 gridF((W + FTW - 1) / FTW, (H + FTH - 1) / FTH, B);
        for (int i = 0; i < STEPS; ++i) {
            const float* src = (i == 0) ? T0 : ((i & 1) ? ping : out);
            float*       dst = (i & 1) ? out : ping;
            if (fast)
                stream_kernel<<<gridS, dim3(NT), 0, stream>>>(src, ug, vg, mask, coef, dst, H, W);
            else
                step_tile<<<gridF, dim3(NT), 0, stream>>>(src, ug, vg, mask, coef, dst, H, W);
        }
    }
}

// Round 12
// 1131.680 us; speedup vs baseline: 1.7814x; 1.0054x over previous
//
#include <hip/hip_runtime.h>

// Ocean advection + 3x3 binomial smoothing, 48 steps, fp32.
//
// ROUND-12: TEMPORAL FUSION x3 + TWO ROWS PER ITERATION.
// Model from rounds 1-11: total = Ndisp x NITER x T_iter; T_iter ~ 1.4us
// fixed stall + 0.23us/barrier + VALU(0.5us), VALUBusy only ~25% -> amortize
// the fixed cost over 2 rows/iter. NITER 26 -> 14, barriers/row 3 -> 1.5.
// Stage offsets (advection needs cross-wave edges only at its OWN row,
// published >=1 iter earlier; smoothing's 3-row edges cross one barrier):
//   R1: A1 @ {r-1, r}          B1
//   R2: S1 @ {r-2, r-1}; A2 @ {r-4, r-3}      B2
//   R3: S2 @ {r-5, r-4}; A3 @ {r-7, r-6}; T-prefetch+eT publish   B3
//   R4: out @ {r-8, r-7} -> store
// r = h0 - 4 + 2j, j = 0..13 (NITER=14). Edge rings depth 16 (span 13 rows),
// slots compile-time (h0 % 16 == 0). Per-phase u/g/m reloads (round-11
// verified, no-spill technique). eT published in R3 so its R1 read next iter
// is >=1 barrier later. Chain-boot garbage confined below first-needed rows
// (a1>=h0-5, s1>=h0-4, a2>=h0-3, s2>=h0-2, a3>=h0-1, out>=h0 all clean).
// Tripwires: WRITE_SIZE must be 32768 KB EXACTLY (VGPR est 105-125 < 128 cap
// of (256,2)); if spilled or dispatch >50us -> revert to 872us K=3 champion.

#define DEG2RAD 0.017453292519943295f
#define R_EARTH 6371000.0f
#define DT_S 600.0f

constexpr int NT    = 256;   // threads per block
constexpr int STRIP = 8;     // legacy stream kernel: rows per wave
constexpr int WPW   = 256;   // legacy stream kernel: cols per wave

__global__ __launch_bounds__(256)
void prep_kernel(const float* __restrict__ lat, const float* __restrict__ lon,
                 float* __restrict__ coef, int H) {
    int h = blockIdx.x * blockDim.x + threadIdx.x;
    if (h < H) {
        float dlon = lon[1] - lon[0];
        coef[h] = 1.0f / (R_EARTH * DEG2RAD * dlon * cosf(lat[h] * DEG2RAD));
    }
    if (h == 0) {
        float dlat = lat[1] - lat[0];
        coef[H] = 1.0f / (R_EARTH * DEG2RAD * dlat);
    }
}

// ------------------- fused 3-step, 2-rows-per-iter kernel -------------------
constexpr int FWAVES = 4;    // waves per block, FWAVES*256 must == W
constexpr int SH3    = 16;   // output rows per block (h0 % 16 == 0!)
constexpr int NIT32  = 14;   // iterations (2 rows each)

__global__ __launch_bounds__(256, 2)
void fused3x2_kernel(const float* __restrict__ Tin, const float* __restrict__ ug,
                     const float* __restrict__ vg, const float* __restrict__ mask,
                     const float* __restrict__ coef, float* __restrict__ Tout,
                     int H, int W) {
    const int lane = threadIdx.x & 63;
    const int wv   = threadIdx.x >> 6;
    const int h0   = blockIdx.x * SH3;
    const int b    = blockIdx.y;
    const int gw   = (wv << 8) + (lane << 2);
    const size_t plane = (size_t)H * W;
    const float* __restrict__ Tb  = Tin + b * plane;
    const float* __restrict__ ugb = ug  + b * plane;
    const float* __restrict__ vgb = vg  + b * plane;
    float* __restrict__ To = Tout + b * plane;
    const float inv_dy = coef[H];
    const bool isL = (lane == 0), isR = (lane == 63);
    const bool domL = (wv == 0), domR = (wv == FWAVES - 1);
    const int wvm = domL ? 0 : wv - 1;            // safe neighbor indices
    const int wvp = domR ? FWAVES - 1 : wv + 1;   // (values unused at domain edge)

    // edge rings: [row & 15][wave][0 = first col, 1 = last col]
    __shared__ float eT [16][FWAVES][2];
    __shared__ float eA1[16][FWAVES][2];
    __shared__ float eS1[16][FWAVES][2];
    __shared__ float eA2[16][FWAVES][2];
    __shared__ float eS2[16][FWAVES][2];
    __shared__ float eA3[16][FWAVES][2];

    auto rowc = [&](int r) { return min(max(r, 0), H - 1); };
    auto ld4 = [&](const float* __restrict__ p, int r) -> float4 {
        return *(const float4*)(p + (size_t)rowc(r) * W + gw);
    };
    const float4 z4 = make_float4(0.f, 0.f, 0.f, 0.f);

    // advect one row: ym/yp are boundary-adjusted y-neighbors (clamped T loads
    // or explicit select for register chains); cLn/cRn cross-wave same-row vals
    auto adv = [&](int row, const float4& ym, const float4& yc, const float4& yp,
                   float cLn, float cRn, const float4& u4, const float4& g4,
                   const float4& m4) -> float4 {
        if (row < 0 || row >= H) return z4;
        const float ix  = coef[row];
        const float sy  = (row == 0 || row == H - 1) ? inv_dy : 0.5f * inv_dy;
        const float sxh = 0.5f * ix;
        float cL = __shfl_up(yc.w, 1);
        float cR = __shfl_down(yc.x, 1);
        float sxx = sxh, sxw = sxh;
        if (isL) { if (domL) { cL = yc.x; sxx = ix; } else cL = cLn; }
        if (isR) { if (domR) { cR = yc.w; sxw = ix; } else cR = cRn; }
        float4 o;
        o.x = yc.x + DT_S * (-(u4.x * ((yc.y - cL ) * sxx) + g4.x * ((yp.x - ym.x) * sy)) * m4.x);
        o.y = yc.y + DT_S * (-(u4.y * ((yc.z - yc.x) * sxh) + g4.y * ((yp.y - ym.y) * sy)) * m4.y);
        o.z = yc.z + DT_S * (-(u4.z * ((yc.w - yc.y) * sxh) + g4.z * ((yp.z - ym.z) * sy)) * m4.z);
        o.w = yc.w + DT_S * (-(u4.w * ((cR  - yc.z) * sxw) + g4.w * ((yp.w - ym.w) * sy)) * m4.w);
        return o;
    };
    // smooth one row (am/ac/ap hold zeros outside domain -> zero pad in y)
    auto smo = [&](int row, const float4& am, const float4& ac, const float4& ap,
                   float vLn, float vRn, const float4& m4) -> float4 {
        if (row < 0 || row >= H) return z4;
        float4 v;
        v.x = am.x + 2.f * ac.x + ap.x;
        v.y = am.y + 2.f * ac.y + ap.y;
        v.z = am.z + 2.f * ac.z + ap.z;
        v.w = am.w + 2.f * ac.w + ap.w;
        float vL = __shfl_up(v.w, 1);
        float vR = __shfl_down(v.x, 1);
        if (isL) vL = domL ? 0.f : vLn;
        if (isR) vR = domR ? 0.f : vRn;
        float4 o;
        o.x = (vL  + 2.f * v.x + v.y) * 0.0625f * m4.x;
        o.y = (v.x + 2.f * v.y + v.z) * 0.0625f * m4.y;
        o.z = (v.y + 2.f * v.z + v.w) * 0.0625f * m4.z;
        o.w = (v.z + 2.f * v.w + vR ) * 0.0625f * m4.w;
        return o;
    };
    auto pub = [&](float (*ring)[FWAVES][2], int slot, const float4& val) {
        if (isL) ring[slot][wv][0] = val.x;
        if (isR) ring[slot][wv][1] = val.w;
    };

    // ---- warm-up: T rows h0-6..h0-3 preloaded; chains zero ----
    float4 t0 = z4, t1 = z4;
    float4 t2 = ld4(Tb, h0 - 6), t3 = ld4(Tb, h0 - 5);
    float4 t4 = ld4(Tb, h0 - 4), t5 = ld4(Tb, h0 - 3);
    pub(eT, 10, t2); pub(eT, 11, t3); pub(eT, 12, t4); pub(eT, 13, t5);
    float4 a1_0 = z4, a1_1 = z4, a1_2 = z4, a1_3 = z4;           // rows r-3..r
    float4 s1_0 = z4, s1_1 = z4, s1_2 = z4, s1_3 = z4, s1_4 = z4; // r-5..r-1
    float4 a2_0 = z4, a2_1 = z4, a2_2 = z4, a2_3 = z4;           // r-6..r-3
    float4 s2_0 = z4, s2_1 = z4, s2_2 = z4, s2_3 = z4, s2_4 = z4; // r-8..r-4
    float4 a3_0 = z4, a3_1 = z4, a3_2 = z4, a3_3 = z4;           // r-9..r-6
    asm volatile("s_waitcnt lgkmcnt(0)" ::: "memory");
    __builtin_amdgcn_s_barrier();

    #pragma unroll
    for (int j = 0; j < NIT32; ++j) {
        const int r = h0 - 4 + 2 * j;            // A1 top row
        auto S = [&](int c) { return (c + 2 * j + 32) & 15; }; // row h0+c+2j -> slot

        // ================= region 1: A1 @ {r-1, r} =================
        t0 = t2; t1 = t3; t2 = t4; t3 = t5;      // T rows r-2..r+1
        float4 uA0 = ld4(ugb, r - 1), gA0 = ld4(vgb, r - 1), mA0 = ld4(mask, r - 1);
        float4 uA1 = ld4(ugb, r),     gA1 = ld4(vgb, r),     mA1 = ld4(mask, r);
        float4 n1 = adv(r - 1, t0, t1, t2, eT[S(-5)][wvm][1], eT[S(-5)][wvp][0], uA0, gA0, mA0);
        float4 n2 = adv(r,     t1, t2, t3, eT[S(-4)][wvm][1], eT[S(-4)][wvp][0], uA1, gA1, mA1);
        pub(eA1, S(-5), n1); pub(eA1, S(-4), n2);
        a1_0 = a1_2; a1_1 = a1_3; a1_2 = n1; a1_3 = n2;   // rows r-3..r
        asm volatile("s_waitcnt lgkmcnt(0)" ::: "memory");
        __builtin_amdgcn_s_barrier();                     // B1

        // ====== region 2: S1 @ {r-2, r-1} then A2 @ {r-4, r-3} ======
        float4 uQ0 = ld4(ugb, r - 4), gQ0 = ld4(vgb, r - 4), mQ0 = ld4(mask, r - 4);
        float4 uQ1 = ld4(ugb, r - 3), gQ1 = ld4(vgb, r - 3), mQ1 = ld4(mask, r - 3);
        float4 mS0 = ld4(mask, r - 2), mS1 = ld4(mask, r - 1);
        float vL0 = eA1[S(-7)][wvm][1] + 2.f * eA1[S(-6)][wvm][1] + eA1[S(-5)][wvm][1];
        float vR0 = eA1[S(-7)][wvp][0] + 2.f * eA1[S(-6)][wvp][0] + eA1[S(-5)][wvp][0];
        float4 sn1 = smo(r - 2, a1_0, a1_1, a1_2, vL0, vR0, mS0);
        float vL1 = eA1[S(-6)][wvm][1] + 2.f * eA1[S(-5)][wvm][1] + eA1[S(-4)][wvm][1];
        float vR1 = eA1[S(-6)][wvp][0] + 2.f * eA1[S(-5)][wvp][0] + eA1[S(-4)][wvp][0];
        float4 sn2 = smo(r - 1, a1_1, a1_2, a1_3, vL1, vR1, mS1);
        pub(eS1, S(-6), sn1); pub(eS1, S(-5), sn2);
        s1_0 = s1_2; s1_1 = s1_3; s1_2 = s1_4; s1_3 = sn1; s1_4 = sn2; // r-5..r-1
        {
            const int q0 = r - 4, q1 = r - 3;     // eS1[q] published prev iter
            float4 ym0 = (q0 == 0)     ? s1_1 : s1_0;
            float4 yp0 = (q0 == H - 1) ? s1_1 : s1_2;
            float4 an1 = adv(q0, ym0, s1_1, yp0, eS1[S(-8)][wvm][1], eS1[S(-8)][wvp][0], uQ0, gQ0, mQ0);
            float4 ym1 = (q1 == 0)     ? s1_2 : s1_1;
            float4 yp1 = (q1 == H - 1) ? s1_2 : s1_3;
            float4 an2 = adv(q1, ym1, s1_2, yp1, eS1[S(-7)][wvm][1], eS1[S(-7)][wvp][0], uQ1, gQ1, mQ1);
            pub(eA2, S(-8), an1); pub(eA2, S(-7), an2);
            a2_0 = a2_2; a2_1 = a2_3; a2_2 = an1; a2_3 = an2;  // r-6..r-3
        }
        asm volatile("s_waitcnt lgkmcnt(0)" ::: "memory");
        __builtin_amdgcn_s_barrier();                     // B2

        // == region 3: S2 @ {r-5, r-4}, A3 @ {r-7, r-6}, T-prefetch ==
        t4 = ld4(Tb, r + 2); t5 = ld4(Tb, r + 3);          // issue early
        float4 uP0 = ld4(ugb, r - 7), gP0 = ld4(vgb, r - 7), mP0 = ld4(mask, r - 7);
        float4 uP1 = ld4(ugb, r - 6), gP1 = ld4(vgb, r - 6), mP1 = ld4(mask, r - 6);
        float4 mT0 = ld4(mask, r - 5), mT1 = ld4(mask, r - 4);
        float wL0 = eA2[S(-10)][wvm][1] + 2.f * eA2[S(-9)][wvm][1] + eA2[S(-8)][wvm][1];
        float wR0 = eA2[S(-10)][wvp][0] + 2.f * eA2[S(-9)][wvp][0] + eA2[S(-8)][wvp][0];
        float4 tn1 = smo(r - 5, a2_0, a2_1, a2_2, wL0, wR0, mT0);
        float wL1 = eA2[S(-9)][wvm][1] + 2.f * eA2[S(-8)][wvm][1] + eA2[S(-7)][wvm][1];
        float wR1 = eA2[S(-9)][wvp][0] + 2.f * eA2[S(-8)][wvp][0] + eA2[S(-7)][wvp][0];
        float4 tn2 = smo(r - 4, a2_1, a2_2, a2_3, wL1, wR1, mT1);
        pub(eS2, S(-9), tn1); pub(eS2, S(-8), tn2);
        s2_0 = s2_2; s2_1 = s2_3; s2_2 = s2_4; s2_3 = tn1; s2_4 = tn2; // r-8..r-4
        {
            const int p0 = r - 7, p1 = r - 6;     // eS2[p] published prev iter
            float4 zm0 = (p0 == 0)     ? s2_1 : s2_0;
            float4 zp0 = (p0 == H - 1) ? s2_1 : s2_2;
            float4 bn1 = adv(p0, zm0, s2_1, zp0, eS2[S(-11)][wvm][1], eS2[S(-11)][wvp][0], uP0, gP0, mP0);
            float4 zm1 = (p1 == 0)     ? s2_2 : s2_1;
            float4 zp1 = (p1 == H - 1) ? s2_2 : s2_3;
            float4 bn2 = adv(p1, zm1, s2_2, zp1, eS2[S(-10)][wvm][1], eS2[S(-10)][wvp][0], uP1, gP1, mP1);
            pub(eA3, S(-11), bn1); pub(eA3, S(-10), bn2);
            a3_0 = a3_2; a3_1 = a3_3; a3_2 = bn1; a3_3 = bn2;  // r-9..r-6
        }
        pub(eT, S(-2), t4); pub(eT, S(-1), t5);   // read next iter R1 (>=1 barrier)
        asm volatile("s_waitcnt lgkmcnt(0)" ::: "memory");
        __builtin_amdgcn_s_barrier();                     // B3

        // ================= region 4: out @ {r-8, r-7} =================
        {
            const int o0 = r - 8, o1 = r - 7;
            if (o0 >= h0 && o0 < H) {
                float4 mO0 = ld4(mask, o0);
                float xL0 = eA3[S(-13)][wvm][1] + 2.f * eA3[S(-12)][wvm][1] + eA3[S(-11)][wvm][1];
                float xR0 = eA3[S(-13)][wvp][0] + 2.f * eA3[S(-12)][wvp][0] + eA3[S(-11)][wvp][0];
                float4 on1 = smo(o0, a3_0, a3_1, a3_2, xL0, xR0, mO0);
                *(float4*)(To + (size_t)o0 * W + gw) = on1;
            }
            if (o1 >= h0 && o1 < H) {
                float4 mO1 = ld4(mask, o1);
                float xL1 = eA3[S(-12)][wvm][1] + 2.f * eA3[S(-11)][wvm][1] + eA3[S(-10)][wvm][1];
                float xR1 = eA3[S(-12)][wvp][0] + 2.f * eA3[S(-11)][wvp][0] + eA3[S(-10)][wvp][0];
                float4 on2 = smo(o1, a3_1, a3_2, a3_3, xL1, xR1, mO1);
                *(float4*)(To + (size_t)o1 * W + gw) = on2;
            }
        }
        // no barrier needed before next R1 (disjoint rings / >=1-barrier reads)
    }
}

// --------- legacy single-step stream kernel (fallback, W % 256 == 0) -------
__global__ __launch_bounds__(256, 4)
void stream_kernel(const float* __restrict__ Tin, const float* __restrict__ ug,
                   const float* __restrict__ vg, const float* __restrict__ mask,
                   const float* __restrict__ coef, float* __restrict__ Tout,
                   int H, int W) {
    const int lane = threadIdx.x & 63;
    const int wv   = threadIdx.x >> 6;
    const int ws   = blockIdx.x * WPW;
    const int hs   = (blockIdx.y * 4 + wv) * STRIP;
    const int b    = blockIdx.z;
    if (hs >= H) return;
    const size_t plane = (size_t)H * W;
    const float* __restrict__ Tb  = Tin + b * plane;
    const float* __restrict__ ugb = ug  + b * plane;
    const float* __restrict__ vgb = vg  + b * plane;
    float* __restrict__ To = Tout + b * plane;
    const float inv_dy = coef[H];
    const bool atL = (ws == 0);
    const bool atR = (ws + WPW >= W);
    const bool isL = (lane == 0);
    const bool isR = (lane == 63);
    const int gw = ws + 4 * lane;

    auto clampr = [&](int r) { return min(max(r, 0), H - 1); };
    auto ldT = [&](int r) -> float4 {
        return *(const float4*)(Tb + (size_t)clampr(r) * W + gw);
    };
    auto ldL = [&](int r) -> float2 {
        float4 q = *(const float4*)(Tb + (size_t)clampr(r) * W + (ws - 4));
        return make_float2(q.z, q.w);
    };
    auto ldR = [&](int r) -> float2 {
        float4 q = *(const float4*)(Tb + (size_t)clampr(r) * W + (ws + WPW));
        return make_float2(q.x, q.y);
    };

    float4 tp, tc, tn;
    float  tLp_w = 0.f; float2 tLc = make_float2(0.f, 0.f), tLn = make_float2(0.f, 0.f);
    float  tRp_x = 0.f; float2 tRc = make_float2(0.f, 0.f), tRn = make_float2(0.f, 0.f);

    auto roll = [&](int rnext) {
        tp = tc; tc = tn; tn = ldT(rnext);
        if (!atL) { tLp_w = tLc.y; tLc = tLn; tLn = ldL(rnext); }
        if (!atR) { tRp_x = tRc.x; tRc = tRn; tRn = ldR(rnext); }
    };

    auto advrow = [&](int r, float4& a, float& aL, float& aR, float4& mOut) {
        if (r < 0 || r >= H) {
            a = make_float4(0.f, 0.f, 0.f, 0.f); aL = 0.f; aR = 0.f;
            mOut = make_float4(0.f, 0.f, 0.f, 0.f); return;
        }
        const size_t ro = (size_t)r * W;
        const float ix  = coef[r];
        const float sy  = (r == 0 || r == H - 1) ? inv_dy : 0.5f * inv_dy;
        const float sxh = 0.5f * ix;
        float4 u4 = *(const float4*)(ugb + ro + gw);
        float4 g4 = *(const float4*)(vgb + ro + gw);
        float4 m4 = *(const float4*)(mask + ro + gw);
        float cLw = __shfl_up(tc.w, 1);
        float cRx = __shfl_down(tc.x, 1);
        float sxx = sxh, sxw = sxh;
        if (isL) { if (atL) { cLw = tc.x; sxx = ix; } else { cLw = tLc.y; } }
        if (isR) { if (atR) { cRx = tc.w; sxw = ix; } else { cRx = tRc.x; } }
        a.x = tc.x + DT_S * (-(u4.x * ((tc.y - cLw) * sxx) + g4.x * ((tn.x - tp.x) * sy)) * m4.x);
        a.y = tc.y + DT_S * (-(u4.y * ((tc.z - tc.x) * sxh) + g4.y * ((tn.y - tp.y) * sy)) * m4.y);
        a.z = tc.z + DT_S * (-(u4.z * ((tc.w - tc.y) * sxh) + g4.z * ((tn.z - tp.z) * sy)) * m4.z);
        a.w = tc.w + DT_S * (-(u4.w * ((cRx - tc.z) * sxw) + g4.w * ((tn.w - tp.w) * sy)) * m4.w);
        if (!atL) {
            float uL = ((const float4*)(ugb + ro + (ws - 4)))->w;
            float gL = ((const float4*)(vgb + ro + (ws - 4)))->w;
            float mL = ((const float4*)(mask + ro + (ws - 4)))->w;
            aL = tLc.y + DT_S * (-(uL * ((tc.x - tLc.x) * sxh) + gL * ((tLn.y - tLp_w) * sy)) * mL);
        } else aL = 0.f;
        if (!atR) {
            float uR = ((const float4*)(ugb + ro + (ws + WPW)))->x;
            float gR = ((const float4*)(vgb + ro + (ws + WPW)))->x;
            float mR = ((const float4*)(mask + ro + (ws + WPW)))->x;
            aR = tRc.x + DT_S * (-(uR * ((tRc.y - tc.w) * sxh) + gR * ((tRn.x - tRp_x) * sy)) * mR);
        } else aR = 0.f;
        mOut = m4;
    };

    tp = ldT(hs - 2); tc = ldT(hs - 1); tn = ldT(hs);
    if (!atL) { float2 q = ldL(hs - 2); tLp_w = q.y; tLc = ldL(hs - 1); tLn = ldL(hs); }
    if (!atR) { float2 q = ldR(hs - 2); tRp_x = q.x; tRc = ldR(hs - 1); tRn = ldR(hs); }

    float4 ap, ac, an, mC, mN, mdum;
    float aLp, aLc, aLn, aRp, aRc, aRn;
    advrow(hs - 1, ap, aLp, aRp, mdum);
    roll(hs + 1);
    advrow(hs, ac, aLc, aRc, mC);

    #pragma unroll
    for (int i = 0; i < STRIP; ++i) {
        const int go = hs + i;
        roll(go + 2);
        advrow(go + 1, an, aLn, aRn, mN);
        if (go < H) {
            float4 v;
            v.x = ap.x + 2.f * ac.x + an.x;
            v.y = ap.y + 2.f * ac.y + an.y;
            v.z = ap.z + 2.f * ac.z + an.z;
            v.w = ap.w + 2.f * ac.w + an.w;
            float vL  = aLp + 2.f * aLc + aLn;
            float vR  = aRp + 2.f * aRc + aRn;
            float vLw = __shfl_up(v.w, 1);
            float vRx = __shfl_down(v.x, 1);
            if (isL) vLw = atL ? 0.f : vL;
            if (isR) vRx = atR ? 0.f : vR;
            float4 o;
            o.x = (vLw + 2.f * v.x + v.y) * 0.0625f * mC.x;
            o.y = (v.x + 2.f * v.y + v.z) * 0.0625f * mC.y;
            o.z = (v.y + 2.f * v.z + v.w) * 0.0625f * mC.z;
            o.w = (v.z + 2.f * v.w + vRx) * 0.0625f * mC.w;
            *(float4*)(To + (size_t)go * W + gw) = o;
        }
        ap = ac; ac = an;
        aLp = aLc; aLc = aLn; aRp = aRc; aRc = aRn;
        mC = mN;
    }
}

// ---------- generic fallback (round-1 LDS tile kernel, validated) ----------
constexpr int FTW = 64, FTH = 32;
constexpr int FSTW = FTW + 4, FSTH = FTH + 4;
constexpr int FMTW = FTW + 2, FMTH = FTH + 2;

__global__ __launch_bounds__(256)
void step_tile(const float* __restrict__ Tin, const float* __restrict__ ug,
               const float* __restrict__ vg, const float* __restrict__ mask,
               const float* __restrict__ coef, float* __restrict__ Tout,
               int H, int W) {
    __shared__ float sT[FSTH][FSTW];
    __shared__ float sM[FMTH][FMTW];
    const int tid = threadIdx.x;
    const int w0 = blockIdx.x * FTW;
    const int h0 = blockIdx.y * FTH;
    const int b  = blockIdx.z;
    const long plane = (long)H * W;
    const float* Tb  = Tin + b * plane;
    const float* ugb = ug  + b * plane;
    const float* vgb = vg  + b * plane;
    const float inv_dy = coef[H];

    for (int i = tid; i < FSTH * FSTW; i += NT) {
        int r = i / FSTW, c = i - r * FSTW;
        int gh = min(max(h0 - 2 + r, 0), H - 1);
        int gw = min(max(w0 - 2 + c, 0), W - 1);
        sT[r][c] = Tb[gh * W + gw];
    }
    __syncthreads();
    for (int i = tid; i < FMTH * FMTW; i += NT) {
        int r = i / FMTW, c = i - r * FMTW;
        int gh = h0 - 1 + r, gw = w0 - 1 + c;
        float v = 0.0f;
        if (gh >= 0 && gh < H && gw >= 0 && gw < W) {
            int sr = r + 1, sc = c + 1;
            float ndy = sT[sr + 1][sc] - sT[sr - 1][sc];
            float ndx = sT[sr][sc + 1] - sT[sr][sc - 1];
            float sy  = (gh == 0 || gh == H - 1) ? inv_dy : 0.5f * inv_dy;
            float ix  = coef[gh];
            float sx  = (gw == 0 || gw == W - 1) ? ix : 0.5f * ix;
            int   gi  = gh * W + gw;
            float F   = -(ugb[gi] * (ndx * sx) + vgb[gi] * (ndy * sy)) * mask[gi];
            v = sT[sr][sc] + DT_S * F;
        }
        sM[r][c] = v;
    }
    __syncthreads();
    float* To = Tout + b * plane;
    for (int i = tid; i < FTH * FTW; i += NT) {
        int r = i >> 6, c = i & (FTW - 1);
        int gh = h0 + r, gw = w0 + c;
        if (gh < H && gw < W) {
            int sr = r + 1, sc = c + 1;
            float s = (sM[sr-1][sc-1] + sM[sr-1][sc+1] + sM[sr+1][sc-1] + sM[sr+1][sc+1])
                    + 2.0f * (sM[sr-1][sc] + sM[sr+1][sc] + sM[sr][sc-1] + sM[sr][sc+1])
                    + 4.0f * sM[sr][sc];
            To[gh * W + gw] = s * 0.0625f * mask[gh * W + gw];
        }
    }
}

extern "C" void kernel_launch(void* const* d_in, const int* in_sizes, int n_in,
                              void* d_out, int out_size, void* d_ws, size_t ws_size,
                              hipStream_t stream) {
    const float* T0   = (const float*)d_in[0];
    const float* ug   = (const float*)d_in[1];
    const float* vg   = (const float*)d_in[2];
    const float* lat  = (const float*)d_in[3];
    const float* lon  = (const float*)d_in[4];
    const float* mask = (const float*)d_in[5];

    const int H = in_sizes[3];
    const int W = in_sizes[4];
    const int B = in_sizes[0] / (H * W);

    float* out  = (float*)d_out;
    float* ping = (float*)d_ws;                 // B*H*W floats
    float* coef = ping + (size_t)B * H * W;     // H+1 floats: 1/dx[h], then 1/dy

    prep_kernel<<<dim3((H + NT - 1) / NT), dim3(NT), 0, stream>>>(lat, lon, coef, H);

    const int STEPS = 48;

    if (W == FWAVES * 256) {
        // fused 3-step path (2 rows/iter): 16 launches, each = 3 sim steps
        dim3 gridF((H + SH3 - 1) / SH3, B);     // 64 x 8 = 512 blocks
        const int NLAUNCH = STEPS / 3;          // 16, even -> last dst == out
        for (int i = 0; i < NLAUNCH; ++i) {
            const float* src = (i == 0) ? T0 : ((i & 1) ? ping : out);
            float*       dst = (i & 1) ? out : ping;
            fused3x2_kernel<<<gridF, dim3(NT), 0, stream>>>(src, ug, vg, mask, coef, dst, H, W);
        }
    } else {
        const bool fast = (W % WPW) == 0;
        dim3 gridS(W / (fast ? WPW : 1), (H + 4 * STRIP - 1) / (4 * STRIP), B);
        dim3 gridF((W + FTW - 1) / FTW, (H + FTH - 1) / FTH, B);
        for (int i = 0; i < STEPS; ++i) {
            const float* src = (i == 0) ? T0 : ((i & 1) ? ping : out);
            float*       dst = (i & 1) ? out : ping;
            if (fast)
                stream_kernel<<<gridS, dim3(NT), 0, stream>>>(src, ug, vg, mask, coef, dst, H, W);
            else
                step_tile<<<gridF, dim3(NT), 0, stream>>>(src, ug, vg, mask, coef, dst, H, W);
        }
    }
}